// Round 1
// baseline (1624.837 us; speedup 1.0000x reference)
//
#include <hip/hip_runtime.h>

#define N_NODES 100000
#define N_EDGES 1600000
#define F_IN 128
#define F_OUT 64
#define BN_EPS 1e-5f

// ---------------- workspace layout (float elements) ----------------
// h:    [0, 6400000)           h = x @ W^T   (N x 64)
// dinv: [6400000, 6500000)     rsqrt(deg)
// sums: [6500000, 6500128)     per-channel sum / sumsq -> scale/bias
// deg:  [6500128, 6600128)     uint32 degree
// flag: [6600128]              1 = edge_index stored as int64, 0 = int32

__device__ __forceinline__ int get_src(const void* ei, int e, int is64) {
    return is64 ? (int)((const long long*)ei)[e] : ((const int*)ei)[e];
}
__device__ __forceinline__ int get_dst(const void* ei, int e, int is64) {
    return is64 ? (int)((const long long*)ei)[N_EDGES + e]
                : ((const int*)ei)[N_EDGES + e];
}

// Detect whether edge_index is int64 or int32 on device.
__global__ void detect_kernel(const void* __restrict__ ei, int* __restrict__ flag) {
    __shared__ int bad;
    if (threadIdx.x == 0) bad = 0;
    __syncthreads();
    int local = 0;
    for (int i = threadIdx.x; i < 1024; i += blockDim.x) {
        long long v = ((const long long*)ei)[i];
        if (v < 0 || v >= N_NODES) local = 1;
    }
    if (local) atomicOr(&bad, 1);
    __syncthreads();
    if (threadIdx.x == 0) *flag = bad ? 0 : 1;
}

// deg = 1 (self loop), sums = 0
__global__ void init_kernel(unsigned* __restrict__ deg, float* __restrict__ sums) {
    int i = blockIdx.x * blockDim.x + threadIdx.x;
    if (i < N_NODES) deg[i] = 1u;
    if (i < 128) sums[i] = 0.f;
}

__global__ void deg_kernel(const void* __restrict__ ei, unsigned* __restrict__ deg,
                           const int* __restrict__ flag) {
    int is64 = *flag;
    int e = blockIdx.x * blockDim.x + threadIdx.x;
    if (e < N_EDGES) {
        int s = get_src(ei, e, is64);
        if ((unsigned)s < N_NODES) atomicAdd(&deg[s], 1u);
    }
}

__global__ void dinv_kernel(const unsigned* __restrict__ deg, float* __restrict__ dinv) {
    int i = blockIdx.x * blockDim.x + threadIdx.x;
    if (i < N_NODES) dinv[i] = rsqrtf((float)deg[i]);
}

// h = x @ W^T.  64 nodes/block, 256 threads.
// thread: og = tid&7 -> outputs {og, og+8, ..., og+56}; ng = tid>>3 -> nodes ng, ng+32.
// W in LDS chunk-major [kc][o][4] so the 8 W reads/iter hit distinct banks.
__global__ __launch_bounds__(256) void gemm_kernel(const float* __restrict__ x,
                                                   const float* __restrict__ W,
                                                   float* __restrict__ h) {
    __shared__ float xs[64 * 132];   // [64 nodes][128 + pad4]
    __shared__ float wt[32 * 256];   // [kc][o][4]
    const int tid = threadIdx.x;
    const int n0 = blockIdx.x * 64;

    // stage x tile: 8192 floats, 8 x float4 per thread
#pragma unroll
    for (int i = 0; i < 8; ++i) {
        int f4 = tid + i * 256;          // float4 index 0..2047
        int n = f4 >> 5;                 // /32 float4s per row
        int k = (f4 & 31) << 2;
        float4 v = make_float4(0.f, 0.f, 0.f, 0.f);
        if (n0 + n < N_NODES) v = *(const float4*)&x[(n0 + n) * F_IN + k];
        *(float4*)&xs[n * 132 + k] = v;
    }
    // stage W: thread t -> o = t&63, kc = (t>>6)+4i. LDS writes contiguous per wave.
#pragma unroll
    for (int i = 0; i < 8; ++i) {
        int o = tid & 63;
        int kc = (tid >> 6) + i * 4;
        float4 v = *(const float4*)&W[o * F_IN + kc * 4];
        *(float4*)&wt[kc * 256 + o * 4] = v;
    }
    __syncthreads();

    const int og = tid & 7;
    const int ng = tid >> 3;    // 0..31
    float acc0[8], acc1[8];
#pragma unroll
    for (int j = 0; j < 8; ++j) { acc0[j] = 0.f; acc1[j] = 0.f; }

    const float4* xs4a = (const float4*)&xs[ng * 132];
    const float4* xs4b = (const float4*)&xs[(ng + 32) * 132];
    const float4* wt4 = (const float4*)wt;
#pragma unroll 4
    for (int kc = 0; kc < 32; ++kc) {
        float4 xa = xs4a[kc];
        float4 xb = xs4b[kc];
#pragma unroll
        for (int j = 0; j < 8; ++j) {
            float4 wv = wt4[kc * 64 + og + 8 * j];
            acc0[j] += xa.x * wv.x + xa.y * wv.y + xa.z * wv.z + xa.w * wv.w;
            acc1[j] += xb.x * wv.x + xb.y * wv.y + xb.z * wv.z + xb.w * wv.w;
        }
    }
    const int na = n0 + ng, nb = n0 + ng + 32;
#pragma unroll
    for (int j = 0; j < 8; ++j) {
        if (na < N_NODES) h[na * F_OUT + og + 8 * j] = acc0[j];
        if (nb < N_NODES) h[nb * F_OUT + og + 8 * j] = acc1[j];
    }
}

// Edge scatter: agg[dst] += h[src] * (dinv[src]*w*dinv[dst]).
// 16 edges/block, 16 lanes/edge, float4 per lane, 4 atomics per lane.
#define EPB 16
__global__ __launch_bounds__(256) void scatter_kernel(const void* __restrict__ ei,
                                                      const float* __restrict__ ew,
                                                      const float* __restrict__ dinv,
                                                      const float* __restrict__ h,
                                                      float* __restrict__ agg,
                                                      const int* __restrict__ flag) {
    __shared__ int s_s[EPB];
    __shared__ int s_d[EPB];
    __shared__ float s_c[EPB];
    const int is64 = *flag;
    const int tid = threadIdx.x;
    const int e0 = blockIdx.x * EPB;
    if (tid < EPB) {
        int e = e0 + tid;
        int s = -1, d = -1;
        float c = 0.f;
        if (e < N_EDGES) {
            s = get_src(ei, e, is64);
            d = get_dst(ei, e, is64);
            if ((unsigned)s < N_NODES && (unsigned)d < N_NODES) {
                c = dinv[s] * ew[e] * dinv[d];
            } else {
                s = -1;
            }
        }
        s_s[tid] = s; s_d[tid] = d; s_c[tid] = c;
    }
    __syncthreads();
    const int el = tid >> 4;          // edge slot 0..15
    const int ci = (tid & 15) << 2;   // channel offset 0,4,...,60
    int s = s_s[el];
    if (s >= 0) {
        float c = s_c[el];
        int d = s_d[el];
        float4 hv = *(const float4*)&h[s * F_OUT + ci];
        float* o = &agg[d * F_OUT + ci];
        atomicAdd(o + 0, hv.x * c);
        atomicAdd(o + 1, hv.y * c);
        atomicAdd(o + 2, hv.z * c);
        atomicAdd(o + 3, hv.w * c);
    }
}

// Add self-loop term, ReLU in place, accumulate per-channel sum/sumsq.
__global__ __launch_bounds__(256) void stats_kernel(const float* __restrict__ h,
                                                    const float* __restrict__ dinv,
                                                    float* __restrict__ agg,
                                                    float* __restrict__ sums) {
    const int c = threadIdx.x & 63;
    const int slot = threadIdx.x >> 6;  // 0..3
    float s1 = 0.f, s2 = 0.f;
    for (int n = blockIdx.x * 4 + slot; n < N_NODES; n += gridDim.x * 4) {
        float di = dinv[n];
        float v = agg[n * F_OUT + c] + h[n * F_OUT + c] * di * di;
        v = fmaxf(v, 0.f);
        agg[n * F_OUT + c] = v;
        s1 += v;
        s2 += v * v;
    }
    __shared__ float r1[256], r2[256];
    r1[threadIdx.x] = s1;
    r2[threadIdx.x] = s2;
    __syncthreads();
    if (threadIdx.x < 64) {
        float a1 = r1[threadIdx.x] + r1[threadIdx.x + 64] + r1[threadIdx.x + 128] + r1[threadIdx.x + 192];
        float a2 = r2[threadIdx.x] + r2[threadIdx.x + 64] + r2[threadIdx.x + 128] + r2[threadIdx.x + 192];
        atomicAdd(&sums[threadIdx.x], a1);
        atomicAdd(&sums[64 + threadIdx.x], a2);
    }
}

// Turn sums into per-channel scale/bias.
__global__ void finalize_kernel(float* __restrict__ sums,
                                const float* __restrict__ gamma,
                                const float* __restrict__ beta) {
    int c = threadIdx.x;  // 64 threads
    const float inv_n = 1.0f / (float)N_NODES;
    float mean = sums[c] * inv_n;
    float var = sums[64 + c] * inv_n - mean * mean;
    float rs = rsqrtf(var + BN_EPS);
    float sc = rs * gamma[c];
    sums[c] = sc;
    sums[64 + c] = beta[c] - mean * sc;
}

__global__ __launch_bounds__(256) void apply_kernel(float* __restrict__ agg,
                                                    const float* __restrict__ sums) {
    int i = blockIdx.x * blockDim.x + threadIdx.x;  // float4 index
    if (i >= N_NODES * 16) return;
    int c4 = (i & 15) << 2;
    float4 v = ((float4*)agg)[i];
    v.x = v.x * sums[c4 + 0] + sums[64 + c4 + 0];
    v.y = v.y * sums[c4 + 1] + sums[64 + c4 + 1];
    v.z = v.z * sums[c4 + 2] + sums[64 + c4 + 2];
    v.w = v.w * sums[c4 + 3] + sums[64 + c4 + 3];
    ((float4*)agg)[i] = v;
}

extern "C" void kernel_launch(void* const* d_in, const int* in_sizes, int n_in,
                              void* d_out, int out_size, void* d_ws, size_t ws_size,
                              hipStream_t stream) {
    const float* x     = (const float*)d_in[0];
    const void*  ei    = d_in[1];
    const float* ew    = (const float*)d_in[2];
    const float* W     = (const float*)d_in[3];
    const float* gamma = (const float*)d_in[4];
    const float* beta  = (const float*)d_in[5];
    float* out = (float*)d_out;
    float* ws  = (float*)d_ws;

    float*    h    = ws;
    float*    dinv = ws + 6400000;
    float*    sums = ws + 6500000;
    unsigned* deg  = (unsigned*)(ws + 6500128);
    int*      flag = (int*)(ws + 6600128);

    hipMemsetAsync(out, 0, (size_t)N_NODES * F_OUT * sizeof(float), stream);
    detect_kernel<<<1, 256, 0, stream>>>(ei, flag);
    init_kernel<<<(N_NODES + 255) / 256, 256, 0, stream>>>(deg, sums);
    deg_kernel<<<N_EDGES / 256, 256, 0, stream>>>(ei, deg, flag);
    dinv_kernel<<<(N_NODES + 255) / 256, 256, 0, stream>>>(deg, dinv);
    gemm_kernel<<<(N_NODES + 63) / 64, 256, 0, stream>>>(x, W, h);
    scatter_kernel<<<N_EDGES / EPB, 256, 0, stream>>>(ei, ew, dinv, h, out, flag);
    stats_kernel<<<1024, 256, 0, stream>>>(h, dinv, out, sums);
    finalize_kernel<<<1, 64, 0, stream>>>(sums, gamma, beta);
    apply_kernel<<<(N_NODES * 16 + 255) / 256, 256, 0, stream>>>(out, sums);
}

// Round 2
// 633.424 us; speedup vs baseline: 2.5652x; 2.5652x over previous
//
#include <hip/hip_runtime.h>

#define N_NODES 100000
#define N_EDGES 1600000
#define F_IN 128
#define F_OUT 64
#define BN_EPS 1e-5f

// ---------------- workspace layout (4-byte elements) ----------------
// h      : [0,         6400000)   h = x @ W^T  (N x 64)
// dinv   : [6400000,   6500000)   rsqrt(src-degree incl self loop)
// sums   : [6500000,   6500128)   per-channel sum/sumsq -> scale/bias
// deg    : [6500128,   6600128)   u32 src-degree (init 1)
// cnt    : [6600128,   6700128)   u32 dst-count (real edges only)
// off    : [6700128,   6800128)   u32 exclusive CSR offsets by dst
// cursor : [6800128,   6900128)   u32 bucket write cursors
// bsum   : [6900128,   6900256)   u32 block sums for scan
// flag   : [6900256]              1 = edge_index int64, 0 = int32
// buck   : [6900258,  10100258)   int2 {src, norm-bits} per edge (8B aligned)

#define SCAN_BLK 1024   // elements per scan block (256 thr x 4)
#define SCAN_NB  ((N_NODES + SCAN_BLK - 1) / SCAN_BLK)   // 98

__device__ __forceinline__ int get_src(const void* ei, int e, int is64) {
    return is64 ? (int)((const long long*)ei)[e] : ((const int*)ei)[e];
}
__device__ __forceinline__ int get_dst(const void* ei, int e, int is64) {
    return is64 ? (int)((const long long*)ei)[N_EDGES + e]
                : ((const int*)ei)[N_EDGES + e];
}

__global__ void detect_kernel(const void* __restrict__ ei, int* __restrict__ flag) {
    __shared__ int bad;
    if (threadIdx.x == 0) bad = 0;
    __syncthreads();
    int local = 0;
    for (int i = threadIdx.x; i < 1024; i += blockDim.x) {
        long long v = ((const long long*)ei)[i];
        if (v < 0 || v >= N_NODES) local = 1;
    }
    if (local) atomicOr(&bad, 1);
    __syncthreads();
    if (threadIdx.x == 0) *flag = bad ? 0 : 1;
}

__global__ void init_kernel(unsigned* __restrict__ deg, unsigned* __restrict__ cnt,
                            float* __restrict__ sums) {
    int i = blockIdx.x * blockDim.x + threadIdx.x;
    if (i < N_NODES) { deg[i] = 1u; cnt[i] = 0u; }
    if (i < 128) sums[i] = 0.f;
}

// Count src-degree (for dinv) and dst-count (for CSR) in one pass.
__global__ void deg_kernel(const void* __restrict__ ei, unsigned* __restrict__ deg,
                           unsigned* __restrict__ cnt, const int* __restrict__ flag) {
    int is64 = *flag;
    int e = blockIdx.x * blockDim.x + threadIdx.x;
    if (e < N_EDGES) {
        int s = get_src(ei, e, is64);
        int d = get_dst(ei, e, is64);
        if ((unsigned)s < N_NODES) atomicAdd(&deg[s], 1u);
        if ((unsigned)d < N_NODES) atomicAdd(&cnt[d], 1u);
    }
}

__global__ void dinv_kernel(const unsigned* __restrict__ deg, float* __restrict__ dinv) {
    int i = blockIdx.x * blockDim.x + threadIdx.x;
    if (i < N_NODES) dinv[i] = rsqrtf((float)deg[i]);
}

// ---- exclusive scan of cnt -> off, 3 small kernels ----
__global__ __launch_bounds__(256) void scan1_kernel(const unsigned* __restrict__ cnt,
                                                    unsigned* __restrict__ off,
                                                    unsigned* __restrict__ bsum) {
    __shared__ unsigned s[256];
    const int tid = threadIdx.x;
    const int base = blockIdx.x * SCAN_BLK + tid * 4;
    unsigned v[4];
#pragma unroll
    for (int k = 0; k < 4; ++k) v[k] = (base + k < N_NODES) ? cnt[base + k] : 0u;
    unsigned tsum = v[0] + v[1] + v[2] + v[3];
    s[tid] = tsum;
    __syncthreads();
    for (int d = 1; d < 256; d <<= 1) {
        unsigned t = (tid >= d) ? s[tid - d] : 0u;
        __syncthreads();
        s[tid] += t;
        __syncthreads();
    }
    unsigned ex = s[tid] - tsum;   // exclusive thread offset within block
    unsigned run = ex;
#pragma unroll
    for (int k = 0; k < 4; ++k) {
        if (base + k < N_NODES) off[base + k] = run;
        run += v[k];
    }
    if (tid == 255) bsum[blockIdx.x] = s[255];
}

__global__ __launch_bounds__(128) void scan2_kernel(unsigned* __restrict__ bsum) {
    __shared__ unsigned s[128];
    const int tid = threadIdx.x;
    unsigned v = (tid < SCAN_NB) ? bsum[tid] : 0u;
    s[tid] = v;
    __syncthreads();
    for (int d = 1; d < 128; d <<= 1) {
        unsigned t = (tid >= d) ? s[tid - d] : 0u;
        __syncthreads();
        s[tid] += t;
        __syncthreads();
    }
    if (tid < SCAN_NB) bsum[tid] = s[tid] - v;  // exclusive
}

__global__ void scan3_kernel(unsigned* __restrict__ off, const unsigned* __restrict__ bsum,
                             unsigned* __restrict__ cursor) {
    int i = blockIdx.x * blockDim.x + threadIdx.x;
    if (i < N_NODES) {
        unsigned o = off[i] + bsum[i >> 10];
        off[i] = o;
        cursor[i] = o;
    }
}

// Scatter edges into dst-buckets: {src, norm} packed as int2.
__global__ void bucket_kernel(const void* __restrict__ ei, const float* __restrict__ ew,
                              const float* __restrict__ dinv, unsigned* __restrict__ cursor,
                              int2* __restrict__ buck, const int* __restrict__ flag) {
    int is64 = *flag;
    int e = blockIdx.x * blockDim.x + threadIdx.x;
    if (e < N_EDGES) {
        int s = get_src(ei, e, is64);
        int d = get_dst(ei, e, is64);
        if ((unsigned)s < N_NODES && (unsigned)d < N_NODES) {
            float norm = dinv[s] * ew[e] * dinv[d];
            unsigned pos = atomicAdd(&cursor[d], 1u);
            buck[pos] = make_int2(s, __float_as_int(norm));
        }
    }
}

// h = x @ W^T.  64 nodes/block, 256 threads. (unchanged from R1 — validated)
__global__ __launch_bounds__(256) void gemm_kernel(const float* __restrict__ x,
                                                   const float* __restrict__ W,
                                                   float* __restrict__ h) {
    __shared__ float xs[64 * 132];
    __shared__ float wt[32 * 256];
    const int tid = threadIdx.x;
    const int n0 = blockIdx.x * 64;
#pragma unroll
    for (int i = 0; i < 8; ++i) {
        int f4 = tid + i * 256;
        int n = f4 >> 5;
        int k = (f4 & 31) << 2;
        float4 v = make_float4(0.f, 0.f, 0.f, 0.f);
        if (n0 + n < N_NODES) v = *(const float4*)&x[(n0 + n) * F_IN + k];
        *(float4*)&xs[n * 132 + k] = v;
    }
#pragma unroll
    for (int i = 0; i < 8; ++i) {
        int o = tid & 63;
        int kc = (tid >> 6) + i * 4;
        float4 v = *(const float4*)&W[o * F_IN + kc * 4];
        *(float4*)&wt[kc * 256 + o * 4] = v;
    }
    __syncthreads();
    const int og = tid & 7;
    const int ng = tid >> 3;
    float acc0[8], acc1[8];
#pragma unroll
    for (int j = 0; j < 8; ++j) { acc0[j] = 0.f; acc1[j] = 0.f; }
    const float4* xs4a = (const float4*)&xs[ng * 132];
    const float4* xs4b = (const float4*)&xs[(ng + 32) * 132];
    const float4* wt4 = (const float4*)wt;
#pragma unroll 4
    for (int kc = 0; kc < 32; ++kc) {
        float4 xa = xs4a[kc];
        float4 xb = xs4b[kc];
#pragma unroll
        for (int j = 0; j < 8; ++j) {
            float4 wv = wt4[kc * 64 + og + 8 * j];
            acc0[j] += xa.x * wv.x + xa.y * wv.y + xa.z * wv.z + xa.w * wv.w;
            acc1[j] += xb.x * wv.x + xb.y * wv.y + xb.z * wv.z + xb.w * wv.w;
        }
    }
    const int na = n0 + ng, nb = n0 + ng + 32;
#pragma unroll
    for (int j = 0; j < 8; ++j) {
        if (na < N_NODES) h[na * F_OUT + og + 8 * j] = acc0[j];
        if (nb < N_NODES) h[nb * F_OUT + og + 8 * j] = acc1[j];
    }
}

// Gather-side aggregation: 16 lanes per node (float4/lane), register accumulate,
// + self loop + ReLU + single plain store. Fused BN sum/sumsq accumulation.
#define AGG_BLOCKS 2048
#define NODE_GROUPS ((N_NODES + 15) / 16)   // 6250
__global__ __launch_bounds__(256) void aggregate_kernel(
    const float* __restrict__ h, const float* __restrict__ dinv,
    const unsigned* __restrict__ off, const unsigned* __restrict__ cnt,
    const int2* __restrict__ buck, float* __restrict__ out,
    float* __restrict__ sums) {
    const int tid = threadIdx.x;
    const int lane16 = tid & 15;   // channel group: channels lane16*4 .. +3
    const int nslot = tid >> 4;    // 0..15
    float s1[4] = {0.f, 0.f, 0.f, 0.f};
    float s2[4] = {0.f, 0.f, 0.f, 0.f};

    for (int g = blockIdx.x; g < NODE_GROUPS; g += AGG_BLOCKS) {
        int n = g * 16 + nslot;
        if (n >= N_NODES) continue;
        float4 acc = make_float4(0.f, 0.f, 0.f, 0.f);
        unsigned o = off[n];
        unsigned c = cnt[n];
        for (unsigned j = 0; j < c; ++j) {
            int2 b = buck[o + j];
            float w = __int_as_float(b.y);
            float4 hv = *(const float4*)&h[(long)b.x * F_OUT + lane16 * 4];
            acc.x += hv.x * w; acc.y += hv.y * w; acc.z += hv.z * w; acc.w += hv.w * w;
        }
        float di = dinv[n];
        float sw = di * di;
        float4 hn = *(const float4*)&h[(long)n * F_OUT + lane16 * 4];
        acc.x = fmaxf(acc.x + hn.x * sw, 0.f);
        acc.y = fmaxf(acc.y + hn.y * sw, 0.f);
        acc.z = fmaxf(acc.z + hn.z * sw, 0.f);
        acc.w = fmaxf(acc.w + hn.w * sw, 0.f);
        *(float4*)&out[(long)n * F_OUT + lane16 * 4] = acc;
        s1[0] += acc.x; s1[1] += acc.y; s1[2] += acc.z; s1[3] += acc.w;
        s2[0] += acc.x * acc.x; s2[1] += acc.y * acc.y;
        s2[2] += acc.z * acc.z; s2[3] += acc.w * acc.w;
    }
    // block reduce: 16 nslots hold the same 4 channels per lane16
    __shared__ float l1[256 * 4];
    __shared__ float l2[256 * 4];
#pragma unroll
    for (int k = 0; k < 4; ++k) { l1[tid * 4 + k] = s1[k]; l2[tid * 4 + k] = s2[k]; }
    __syncthreads();
    if (tid < 16) {   // one thread per lane16 group
        float a1[4] = {0.f, 0.f, 0.f, 0.f};
        float a2[4] = {0.f, 0.f, 0.f, 0.f};
        for (int s = 0; s < 16; ++s) {
            int t = s * 16 + tid;
#pragma unroll
            for (int k = 0; k < 4; ++k) { a1[k] += l1[t * 4 + k]; a2[k] += l2[t * 4 + k]; }
        }
#pragma unroll
        for (int k = 0; k < 4; ++k) {
            atomicAdd(&sums[tid * 4 + k], a1[k]);
            atomicAdd(&sums[64 + tid * 4 + k], a2[k]);
        }
    }
}

__global__ void finalize_kernel(float* __restrict__ sums,
                                const float* __restrict__ gamma,
                                const float* __restrict__ beta) {
    int c = threadIdx.x;  // 64 threads
    const float inv_n = 1.0f / (float)N_NODES;
    float mean = sums[c] * inv_n;
    float var = sums[64 + c] * inv_n - mean * mean;
    float rs = rsqrtf(var + BN_EPS);
    float sc = rs * gamma[c];
    sums[c] = sc;
    sums[64 + c] = beta[c] - mean * sc;
}

__global__ __launch_bounds__(256) void apply_kernel(float* __restrict__ agg,
                                                    const float* __restrict__ sums) {
    int i = blockIdx.x * blockDim.x + threadIdx.x;  // float4 index
    if (i >= N_NODES * 16) return;
    int c4 = (i & 15) << 2;
    float4 v = ((float4*)agg)[i];
    v.x = v.x * sums[c4 + 0] + sums[64 + c4 + 0];
    v.y = v.y * sums[c4 + 1] + sums[64 + c4 + 1];
    v.z = v.z * sums[c4 + 2] + sums[64 + c4 + 2];
    v.w = v.w * sums[c4 + 3] + sums[64 + c4 + 3];
    ((float4*)agg)[i] = v;
}

extern "C" void kernel_launch(void* const* d_in, const int* in_sizes, int n_in,
                              void* d_out, int out_size, void* d_ws, size_t ws_size,
                              hipStream_t stream) {
    const float* x     = (const float*)d_in[0];
    const void*  ei    = d_in[1];
    const float* ew    = (const float*)d_in[2];
    const float* W     = (const float*)d_in[3];
    const float* gamma = (const float*)d_in[4];
    const float* beta  = (const float*)d_in[5];
    float* out = (float*)d_out;
    float* ws  = (float*)d_ws;

    float*    h      = ws;
    float*    dinv   = ws + 6400000;
    float*    sums   = ws + 6500000;
    unsigned* deg    = (unsigned*)(ws + 6500128);
    unsigned* cnt    = (unsigned*)(ws + 6600128);
    unsigned* off    = (unsigned*)(ws + 6700128);
    unsigned* cursor = (unsigned*)(ws + 6800128);
    unsigned* bsum   = (unsigned*)(ws + 6900128);
    int*      flag   = (int*)(ws + 6900256);
    int2*     buck   = (int2*)(ws + 6900258);

    detect_kernel<<<1, 256, 0, stream>>>(ei, flag);
    init_kernel<<<(N_NODES + 255) / 256, 256, 0, stream>>>(deg, cnt, sums);
    deg_kernel<<<N_EDGES / 256, 256, 0, stream>>>(ei, deg, cnt, flag);
    dinv_kernel<<<(N_NODES + 255) / 256, 256, 0, stream>>>(deg, dinv);
    scan1_kernel<<<SCAN_NB, 256, 0, stream>>>(cnt, off, bsum);
    scan2_kernel<<<1, 128, 0, stream>>>(bsum);
    scan3_kernel<<<(N_NODES + 255) / 256, 256, 0, stream>>>(off, bsum, cursor);
    gemm_kernel<<<(N_NODES + 63) / 64, 256, 0, stream>>>(x, W, h);
    bucket_kernel<<<N_EDGES / 256, 256, 0, stream>>>(ei, ew, dinv, cursor, buck, flag);
    aggregate_kernel<<<AGG_BLOCKS, 256, 0, stream>>>(h, dinv, off, cnt, buck, out, sums);
    finalize_kernel<<<1, 64, 0, stream>>>(sums, gamma, beta);
    apply_kernel<<<(N_NODES * 16 + 255) / 256, 256, 0, stream>>>(out, sums);
}

// Round 3
// 476.134 us; speedup vs baseline: 3.4126x; 1.3303x over previous
//
#include <hip/hip_runtime.h>

#define N_NODES 100000
#define N_EDGES 1600000
#define F_IN 128
#define F_OUT 64
#define BN_EPS 1e-5f

// ---------------- workspace layout (4-byte elements) ----------------
// h      : [0,         6400000)   h = x @ W^T  (N x 64)
// dinv   : [6400000,   6500000)   rsqrt(src-degree incl self loop)
// sums   : [6500000,   6500128)   per-channel sum/sumsq -> scale/bias
// deg    : [6500128,   6600128)   u32 src-degree (init 1)
// cnt    : [6600128,   6700128)   u32 dst-count (both-valid edges)
// off    : [6700128,   6800128)   u32 exclusive CSR offsets by dst
// cursor : [6800128,   6900128)   u32 bucket write cursors
// bsum   : [6900128,   6900256)   u32 block sums for scan
// flag   : [6900256]              1 = edge_index int64, 0 = int32
// buck   : [6900258,  10100258)   int2 {src, norm-bits} per edge (8B aligned)

#define SCAN_BLK 1024
#define SCAN_NB  ((N_NODES + SCAN_BLK - 1) / SCAN_BLK)   // 98

__global__ void detect_kernel(const void* __restrict__ ei, int* __restrict__ flag) {
    __shared__ int bad;
    if (threadIdx.x == 0) bad = 0;
    __syncthreads();
    int local = 0;
    for (int i = threadIdx.x; i < 1024; i += blockDim.x) {
        long long v = ((const long long*)ei)[i];
        if (v < 0 || v >= N_NODES) local = 1;
    }
    if (local) atomicOr(&bad, 1);
    __syncthreads();
    if (threadIdx.x == 0) *flag = bad ? 0 : 1;
}

__global__ void init_kernel(unsigned* __restrict__ deg, unsigned* __restrict__ cnt,
                            float* __restrict__ sums) {
    int i = blockIdx.x * blockDim.x + threadIdx.x;
    if (i < N_NODES) { deg[i] = 1u; cnt[i] = 0u; }
    if (i < 128) sums[i] = 0.f;
}

// 2 edges/thread, 16B index loads. deg[s] when s valid; cnt[d] when BOTH valid
// (cnt must equal the number of entries bucket_kernel will place).
__global__ __launch_bounds__(256) void deg_kernel(const void* __restrict__ ei,
                                                  unsigned* __restrict__ deg,
                                                  unsigned* __restrict__ cnt,
                                                  const int* __restrict__ flag) {
    int e = (blockIdx.x * blockDim.x + threadIdx.x) * 2;
    if (e >= N_EDGES) return;
    int s0, s1, d0, d1;
    if (*flag) {
        const long long* p = (const long long*)ei;
        longlong2 sv = *(const longlong2*)&p[e];
        longlong2 dv = *(const longlong2*)&p[N_EDGES + e];
        s0 = (int)sv.x; s1 = (int)sv.y; d0 = (int)dv.x; d1 = (int)dv.y;
    } else {
        const int* p = (const int*)ei;
        int2 sv = *(const int2*)&p[e];
        int2 dv = *(const int2*)&p[N_EDGES + e];
        s0 = sv.x; s1 = sv.y; d0 = dv.x; d1 = dv.y;
    }
    if ((unsigned)s0 < N_NODES) atomicAdd(&deg[s0], 1u);
    if ((unsigned)s1 < N_NODES) atomicAdd(&deg[s1], 1u);
    if ((unsigned)s0 < N_NODES && (unsigned)d0 < N_NODES) atomicAdd(&cnt[d0], 1u);
    if ((unsigned)s1 < N_NODES && (unsigned)d1 < N_NODES) atomicAdd(&cnt[d1], 1u);
}

// ---- exclusive scan of cnt -> off ----
__global__ __launch_bounds__(256) void scan1_kernel(const unsigned* __restrict__ cnt,
                                                    unsigned* __restrict__ off,
                                                    unsigned* __restrict__ bsum) {
    __shared__ unsigned s[256];
    const int tid = threadIdx.x;
    const int base = blockIdx.x * SCAN_BLK + tid * 4;
    unsigned v[4];
#pragma unroll
    for (int k = 0; k < 4; ++k) v[k] = (base + k < N_NODES) ? cnt[base + k] : 0u;
    unsigned tsum = v[0] + v[1] + v[2] + v[3];
    s[tid] = tsum;
    __syncthreads();
    for (int d = 1; d < 256; d <<= 1) {
        unsigned t = (tid >= d) ? s[tid - d] : 0u;
        __syncthreads();
        s[tid] += t;
        __syncthreads();
    }
    unsigned run = s[tid] - tsum;
#pragma unroll
    for (int k = 0; k < 4; ++k) {
        if (base + k < N_NODES) off[base + k] = run;
        run += v[k];
    }
    if (tid == 255) bsum[blockIdx.x] = s[255];
}

__global__ __launch_bounds__(128) void scan2_kernel(unsigned* __restrict__ bsum) {
    __shared__ unsigned s[128];
    const int tid = threadIdx.x;
    unsigned v = (tid < SCAN_NB) ? bsum[tid] : 0u;
    s[tid] = v;
    __syncthreads();
    for (int d = 1; d < 128; d <<= 1) {
        unsigned t = (tid >= d) ? s[tid - d] : 0u;
        __syncthreads();
        s[tid] += t;
        __syncthreads();
    }
    if (tid < SCAN_NB) bsum[tid] = s[tid] - v;
}

// finalize offsets + cursors, and dinv (fused — deg is final here)
__global__ void scan3_kernel(unsigned* __restrict__ off, const unsigned* __restrict__ bsum,
                             unsigned* __restrict__ cursor,
                             const unsigned* __restrict__ deg, float* __restrict__ dinv) {
    int i = blockIdx.x * blockDim.x + threadIdx.x;
    if (i < N_NODES) {
        unsigned o = off[i] + bsum[i >> 10];
        off[i] = o;
        cursor[i] = o;
        dinv[i] = rsqrtf((float)deg[i]);
    }
}

// Place edges into dst-buckets: {src, norm-bits}. 2 edges/thread.
__global__ __launch_bounds__(256) void bucket_kernel(const void* __restrict__ ei,
                                                     const float* __restrict__ ew,
                                                     const float* __restrict__ dinv,
                                                     unsigned* __restrict__ cursor,
                                                     int2* __restrict__ buck,
                                                     const int* __restrict__ flag) {
    int e = (blockIdx.x * blockDim.x + threadIdx.x) * 2;
    if (e >= N_EDGES) return;
    int s0, s1, d0, d1;
    if (*flag) {
        const long long* p = (const long long*)ei;
        longlong2 sv = *(const longlong2*)&p[e];
        longlong2 dv = *(const longlong2*)&p[N_EDGES + e];
        s0 = (int)sv.x; s1 = (int)sv.y; d0 = (int)dv.x; d1 = (int)dv.y;
    } else {
        const int* p = (const int*)ei;
        int2 sv = *(const int2*)&p[e];
        int2 dv = *(const int2*)&p[N_EDGES + e];
        s0 = sv.x; s1 = sv.y; d0 = dv.x; d1 = dv.y;
    }
    float2 wv = *(const float2*)&ew[e];
    if ((unsigned)s0 < N_NODES && (unsigned)d0 < N_NODES) {
        float norm = dinv[s0] * wv.x * dinv[d0];
        unsigned pos = atomicAdd(&cursor[d0], 1u);
        buck[pos] = make_int2(s0, __float_as_int(norm));
    }
    if ((unsigned)s1 < N_NODES && (unsigned)d1 < N_NODES) {
        float norm = dinv[s1] * wv.y * dinv[d1];
        unsigned pos = atomicAdd(&cursor[d1], 1u);
        buck[pos] = make_int2(s1, __float_as_int(norm));
    }
}

// h = x @ W^T.  64 nodes/block, 256 threads. (validated R1/R2)
__global__ __launch_bounds__(256) void gemm_kernel(const float* __restrict__ x,
                                                   const float* __restrict__ W,
                                                   float* __restrict__ h) {
    __shared__ float xs[64 * 132];
    __shared__ float wt[32 * 256];
    const int tid = threadIdx.x;
    const int n0 = blockIdx.x * 64;
#pragma unroll
    for (int i = 0; i < 8; ++i) {
        int f4 = tid + i * 256;
        int n = f4 >> 5;
        int k = (f4 & 31) << 2;
        float4 v = make_float4(0.f, 0.f, 0.f, 0.f);
        if (n0 + n < N_NODES) v = *(const float4*)&x[(n0 + n) * F_IN + k];
        *(float4*)&xs[n * 132 + k] = v;
    }
#pragma unroll
    for (int i = 0; i < 8; ++i) {
        int o = tid & 63;
        int kc = (tid >> 6) + i * 4;
        float4 v = *(const float4*)&W[o * F_IN + kc * 4];
        *(float4*)&wt[kc * 256 + o * 4] = v;
    }
    __syncthreads();
    const int og = tid & 7;
    const int ng = tid >> 3;
    float acc0[8], acc1[8];
#pragma unroll
    for (int j = 0; j < 8; ++j) { acc0[j] = 0.f; acc1[j] = 0.f; }
    const float4* xs4a = (const float4*)&xs[ng * 132];
    const float4* xs4b = (const float4*)&xs[(ng + 32) * 132];
    const float4* wt4 = (const float4*)wt;
#pragma unroll 4
    for (int kc = 0; kc < 32; ++kc) {
        float4 xa = xs4a[kc];
        float4 xb = xs4b[kc];
#pragma unroll
        for (int j = 0; j < 8; ++j) {
            float4 wv = wt4[kc * 64 + og + 8 * j];
            acc0[j] += xa.x * wv.x + xa.y * wv.y + xa.z * wv.z + xa.w * wv.w;
            acc1[j] += xb.x * wv.x + xb.y * wv.y + xb.z * wv.z + xb.w * wv.w;
        }
    }
    const int na = n0 + ng, nb = n0 + ng + 32;
#pragma unroll
    for (int j = 0; j < 8; ++j) {
        if (na < N_NODES) h[na * F_OUT + og + 8 * j] = acc0[j];
        if (nb < N_NODES) h[nb * F_OUT + og + 8 * j] = acc1[j];
    }
}

// Wave-per-node aggregation: 64 lanes = 4 edge slots x 16 channel lanes.
// 2x unroll over slots -> 8 independent buck->h load chains per wave.
// Loop count is wave-uniform (no divergence). Grid-stride keeps BN atomics low.
#define AGG_BLOCKS 2048
#define AGG_WAVES  (AGG_BLOCKS * 4)
__global__ __launch_bounds__(256) void aggregate_kernel(
    const float* __restrict__ h, const float* __restrict__ dinv,
    const unsigned* __restrict__ off, const unsigned* __restrict__ cnt,
    const int2* __restrict__ buck, float* __restrict__ out,
    float* __restrict__ sums) {
    const int tid = threadIdx.x;
    const int wv = tid >> 6;      // wave in block 0..3
    const int lane = tid & 63;
    const int es = lane >> 4;     // edge slot 0..3
    const int cl = lane & 15;     // channel group (4 channels)
    float s1[4] = {0.f, 0.f, 0.f, 0.f};
    float s2[4] = {0.f, 0.f, 0.f, 0.f};

    for (int n = blockIdx.x * 4 + wv; n < N_NODES; n += AGG_WAVES) {
        const unsigned o = off[n];
        const unsigned c = cnt[n];
        float4 a0 = make_float4(0.f, 0.f, 0.f, 0.f);
        float4 a1 = make_float4(0.f, 0.f, 0.f, 0.f);
        unsigned j = es;
        for (; j + 4 < c; j += 8) {
            int2 b1 = buck[o + j];
            int2 b2 = buck[o + j + 4];
            float4 h1 = *(const float4*)&h[(long)b1.x * F_OUT + cl * 4];
            float4 h2 = *(const float4*)&h[(long)b2.x * F_OUT + cl * 4];
            float w1 = __int_as_float(b1.y);
            float w2 = __int_as_float(b2.y);
            a0.x += h1.x * w1; a0.y += h1.y * w1; a0.z += h1.z * w1; a0.w += h1.w * w1;
            a1.x += h2.x * w2; a1.y += h2.y * w2; a1.z += h2.z * w2; a1.w += h2.w * w2;
        }
        if (j < c) {
            int2 b = buck[o + j];
            float w = __int_as_float(b.y);
            float4 hv = *(const float4*)&h[(long)b.x * F_OUT + cl * 4];
            a0.x += hv.x * w; a0.y += hv.y * w; a0.z += hv.z * w; a0.w += hv.w * w;
        }
        a0.x += a1.x; a0.y += a1.y; a0.z += a1.z; a0.w += a1.w;
        // reduce across the 4 edge slots (lanes differing in bits 4-5)
        a0.x += __shfl_xor(a0.x, 16); a0.y += __shfl_xor(a0.y, 16);
        a0.z += __shfl_xor(a0.z, 16); a0.w += __shfl_xor(a0.w, 16);
        a0.x += __shfl_xor(a0.x, 32); a0.y += __shfl_xor(a0.y, 32);
        a0.z += __shfl_xor(a0.z, 32); a0.w += __shfl_xor(a0.w, 32);
        if (es == 0) {
            float di = dinv[n];
            float sw = di * di;
            float4 hn = *(const float4*)&h[(long)n * F_OUT + cl * 4];
            a0.x = fmaxf(fmaf(hn.x, sw, a0.x), 0.f);
            a0.y = fmaxf(fmaf(hn.y, sw, a0.y), 0.f);
            a0.z = fmaxf(fmaf(hn.z, sw, a0.z), 0.f);
            a0.w = fmaxf(fmaf(hn.w, sw, a0.w), 0.f);
            *(float4*)&out[(long)n * F_OUT + cl * 4] = a0;
            s1[0] += a0.x; s1[1] += a0.y; s1[2] += a0.z; s1[3] += a0.w;
            s2[0] += a0.x * a0.x; s2[1] += a0.y * a0.y;
            s2[2] += a0.z * a0.z; s2[3] += a0.w * a0.w;
        }
    }
    __shared__ float l1[256];   // [wave][64 channels]
    __shared__ float l2[256];
    if (es == 0) {
#pragma unroll
        for (int k = 0; k < 4; ++k) {
            l1[wv * 64 + cl * 4 + k] = s1[k];
            l2[wv * 64 + cl * 4 + k] = s2[k];
        }
    }
    __syncthreads();
    if (tid < 64) {
        float b1 = l1[tid] + l1[64 + tid] + l1[128 + tid] + l1[192 + tid];
        float b2 = l2[tid] + l2[64 + tid] + l2[128 + tid] + l2[192 + tid];
        atomicAdd(&sums[tid], b1);
        atomicAdd(&sums[64 + tid], b2);
    }
}

__global__ void finalize_kernel(float* __restrict__ sums,
                                const float* __restrict__ gamma,
                                const float* __restrict__ beta) {
    int c = threadIdx.x;  // 64 threads
    const float inv_n = 1.0f / (float)N_NODES;
    float mean = sums[c] * inv_n;
    float var = sums[64 + c] * inv_n - mean * mean;
    float rs = rsqrtf(var + BN_EPS);
    float sc = rs * gamma[c];
    sums[c] = sc;
    sums[64 + c] = beta[c] - mean * sc;
}

__global__ __launch_bounds__(256) void apply_kernel(float* __restrict__ agg,
                                                    const float* __restrict__ sums) {
    int i = blockIdx.x * blockDim.x + threadIdx.x;
    if (i >= N_NODES * 16) return;
    int c4 = (i & 15) << 2;
    float4 v = ((float4*)agg)[i];
    v.x = v.x * sums[c4 + 0] + sums[64 + c4 + 0];
    v.y = v.y * sums[c4 + 1] + sums[64 + c4 + 1];
    v.z = v.z * sums[c4 + 2] + sums[64 + c4 + 2];
    v.w = v.w * sums[c4 + 3] + sums[64 + c4 + 3];
    ((float4*)agg)[i] = v;
}

extern "C" void kernel_launch(void* const* d_in, const int* in_sizes, int n_in,
                              void* d_out, int out_size, void* d_ws, size_t ws_size,
                              hipStream_t stream) {
    const float* x     = (const float*)d_in[0];
    const void*  ei    = d_in[1];
    const float* ew    = (const float*)d_in[2];
    const float* W     = (const float*)d_in[3];
    const float* gamma = (const float*)d_in[4];
    const float* beta  = (const float*)d_in[5];
    float* out = (float*)d_out;
    float* ws  = (float*)d_ws;

    float*    h      = ws;
    float*    dinv   = ws + 6400000;
    float*    sums   = ws + 6500000;
    unsigned* deg    = (unsigned*)(ws + 6500128);
    unsigned* cnt    = (unsigned*)(ws + 6600128);
    unsigned* off    = (unsigned*)(ws + 6700128);
    unsigned* cursor = (unsigned*)(ws + 6800128);
    unsigned* bsum   = (unsigned*)(ws + 6900128);
    int*      flag   = (int*)(ws + 6900256);
    int2*     buck   = (int2*)(ws + 6900258);

    detect_kernel<<<1, 256, 0, stream>>>(ei, flag);
    init_kernel<<<(N_NODES + 255) / 256, 256, 0, stream>>>(deg, cnt, sums);
    deg_kernel<<<N_EDGES / 512, 256, 0, stream>>>(ei, deg, cnt, flag);
    scan1_kernel<<<SCAN_NB, 256, 0, stream>>>(cnt, off, bsum);
    scan2_kernel<<<1, 128, 0, stream>>>(bsum);
    scan3_kernel<<<(N_NODES + 255) / 256, 256, 0, stream>>>(off, bsum, cursor, deg, dinv);
    gemm_kernel<<<(N_NODES + 63) / 64, 256, 0, stream>>>(x, W, h);
    bucket_kernel<<<N_EDGES / 512, 256, 0, stream>>>(ei, ew, dinv, cursor, buck, flag);
    aggregate_kernel<<<AGG_BLOCKS, 256, 0, stream>>>(h, dinv, off, cnt, buck, out, sums);
    finalize_kernel<<<1, 64, 0, stream>>>(sums, gamma, beta);
    apply_kernel<<<(N_NODES * 16 + 255) / 256, 256, 0, stream>>>(out, sums);
}

// Round 4
// 374.248 us; speedup vs baseline: 4.3416x; 1.2722x over previous
//
#include <hip/hip_runtime.h>

#define N_NODES 100000
#define N_EDGES 1600000
#define F_IN 128
#define F_OUT 64
#define BN_EPS 1e-5f

#define NPART 8            // node partitions
#define NCHUNK 64          // edge chunks
#define PSIZE 12500        // N_NODES / NPART (nodes per partition)
#define CHUNK_E 25000      // N_EDGES / NCHUNK (edges per chunk)

#define SCAN_BLK 1024
#define SCAN_NB  ((N_NODES + SCAN_BLK - 1) / SCAN_BLK)   // 98

// ---------------- workspace layout (4-byte elements) ----------------
// hp     : [0,        6400000)   partial histograms (count/place), THEN h (gemm on)
// buck   : [6400000,  9600000)   int2 {src, norm-bits} per edge
// dinv   : [9600000,  9700000)
// sums   : [9700000,  9700128)
// cnt    : [9700128,  9800128)
// off    : [9800128,  9900128)
// bsum   : [9900128,  9900256)
// flag   : [9900256]

__global__ void detect_kernel(const void* __restrict__ ei, int* __restrict__ flag) {
    __shared__ int bad;
    if (threadIdx.x == 0) bad = 0;
    __syncthreads();
    int local = 0;
    for (int i = threadIdx.x; i < 1024; i += blockDim.x) {
        long long v = ((const long long*)ei)[i];
        if (v < 0 || v >= N_NODES) local = 1;
    }
    if (local) atomicOr(&bad, 1);
    __syncthreads();
    if (threadIdx.x == 0) *flag = bad ? 0 : 1;
}

__device__ __forceinline__ void load_edges(const void* ei, int e, int is64,
                                           int& s0, int& s1, int& d0, int& d1) {
    if (is64) {
        const long long* q = (const long long*)ei;
        longlong2 sv = *(const longlong2*)&q[e];
        longlong2 dv = *(const longlong2*)&q[N_EDGES + e];
        s0 = (int)sv.x; s1 = (int)sv.y; d0 = (int)dv.x; d1 = (int)dv.y;
    } else {
        const int* q = (const int*)ei;
        int2 sv = *(const int2*)&q[e];
        int2 dv = *(const int2*)&q[N_EDGES + e];
        s0 = sv.x; s1 = sv.y; d0 = dv.x; d1 = dv.y;
    }
}

// Block (p,b): histogram chunk b for node range p into LDS, flush plain stores.
// Packed u32 bin: src-degree in low16, dst-count in high16.
__global__ __launch_bounds__(512) void count_kernel(const void* __restrict__ ei,
                                                    unsigned* __restrict__ partial,
                                                    const int* __restrict__ flag) {
    __shared__ unsigned bins[PSIZE];
    const int tid = threadIdx.x;
    const int p = blockIdx.x % NPART;   // same-chunk blocks adjacent -> L2/L3 share
    const int b = blockIdx.x / NPART;
    const int p0 = p * PSIZE;
    for (int i = tid; i < PSIZE; i += 512) bins[i] = 0u;
    __syncthreads();
    const int is64 = *flag;
    const int e0 = b * CHUNK_E;
    for (int i = tid * 2; i < CHUNK_E; i += 1024) {
        int s0, s1, d0, d1;
        load_edges(ei, e0 + i, is64, s0, s1, d0, d1);
        if ((unsigned)(s0 - p0) < PSIZE) atomicAdd(&bins[s0 - p0], 1u);
        if ((unsigned)(s1 - p0) < PSIZE) atomicAdd(&bins[s1 - p0], 1u);
        if ((unsigned)s0 < N_NODES && (unsigned)(d0 - p0) < PSIZE)
            atomicAdd(&bins[d0 - p0], 0x10000u);
        if ((unsigned)s1 < N_NODES && (unsigned)(d1 - p0) < PSIZE)
            atomicAdd(&bins[d1 - p0], 0x10000u);
    }
    __syncthreads();
    unsigned* dst = &partial[(unsigned)blockIdx.x * PSIZE];
    for (int i = tid; i < PSIZE; i += 512) dst[i] = bins[i];
}

// Per node: total deg -> dinv, total cnt -> cnt; overwrite each chunk slice
// entry with the exclusive prefix of cnt across chunks (placement base).
__global__ __launch_bounds__(256) void reduce_kernel(unsigned* __restrict__ partial,
                                                     unsigned* __restrict__ cnt,
                                                     float* __restrict__ dinv,
                                                     float* __restrict__ sums) {
    int n = blockIdx.x * 256 + threadIdx.x;
    if (n < 128) sums[n] = 0.f;
    if (n >= N_NODES) return;
    unsigned p = (unsigned)n / PSIZE;
    unsigned i = (unsigned)n % PSIZE;
    unsigned run = 0, degt = 0;
    unsigned addr = p * PSIZE + i;
#pragma unroll 8
    for (int b = 0; b < NCHUNK; ++b) {
        unsigned v = partial[addr];
        partial[addr] = run;
        run += v >> 16;
        degt += v & 0xFFFFu;
        addr += NPART * PSIZE;
    }
    cnt[n] = run;
    dinv[n] = rsqrtf((float)(degt + 1u));   // +1 self loop
}

// ---- exclusive scan of cnt -> off ----
__global__ __launch_bounds__(256) void scan1_kernel(const unsigned* __restrict__ cnt,
                                                    unsigned* __restrict__ off,
                                                    unsigned* __restrict__ bsum) {
    __shared__ unsigned s[256];
    const int tid = threadIdx.x;
    const int base = blockIdx.x * SCAN_BLK + tid * 4;
    unsigned v[4];
#pragma unroll
    for (int k = 0; k < 4; ++k) v[k] = (base + k < N_NODES) ? cnt[base + k] : 0u;
    unsigned tsum = v[0] + v[1] + v[2] + v[3];
    s[tid] = tsum;
    __syncthreads();
    for (int d = 1; d < 256; d <<= 1) {
        unsigned t = (tid >= d) ? s[tid - d] : 0u;
        __syncthreads();
        s[tid] += t;
        __syncthreads();
    }
    unsigned run = s[tid] - tsum;
#pragma unroll
    for (int k = 0; k < 4; ++k) {
        if (base + k < N_NODES) off[base + k] = run;
        run += v[k];
    }
    if (tid == 255) bsum[blockIdx.x] = s[255];
}

__global__ __launch_bounds__(128) void scan2_kernel(unsigned* __restrict__ bsum) {
    __shared__ unsigned s[128];
    const int tid = threadIdx.x;
    unsigned v = (tid < SCAN_NB) ? bsum[tid] : 0u;
    s[tid] = v;
    __syncthreads();
    for (int d = 1; d < 128; d <<= 1) {
        unsigned t = (tid >= d) ? s[tid - d] : 0u;
        __syncthreads();
        s[tid] += t;
        __syncthreads();
    }
    if (tid < SCAN_NB) bsum[tid] = s[tid] - v;
}

__global__ void scan3_kernel(unsigned* __restrict__ off, const unsigned* __restrict__ bsum) {
    int i = blockIdx.x * blockDim.x + threadIdx.x;
    if (i < N_NODES) off[i] += bsum[i >> 10];
}

// Deterministic placement: slot = off[d] + chunk-prefix + LDS-local rank.
// No global atomics; payload writes are dense within the partition's CSR region.
__global__ __launch_bounds__(512) void place_kernel(const void* __restrict__ ei,
                                                    const float* __restrict__ ew,
                                                    const float* __restrict__ dinv,
                                                    const unsigned* __restrict__ off,
                                                    const unsigned* __restrict__ partial,
                                                    int2* __restrict__ buck,
                                                    const int* __restrict__ flag) {
    __shared__ unsigned lcur[PSIZE];
    const int tid = threadIdx.x;
    const int p = blockIdx.x % NPART;
    const int b = blockIdx.x / NPART;
    const int p0 = p * PSIZE;
    for (int i = tid; i < PSIZE; i += 512) lcur[i] = 0u;
    __syncthreads();
    const int is64 = *flag;
    const int e0 = b * CHUNK_E;
    const unsigned* pref = &partial[(unsigned)blockIdx.x * PSIZE];
    for (int i = tid * 2; i < CHUNK_E; i += 1024) {
        int s0, s1, d0, d1;
        load_edges(ei, e0 + i, is64, s0, s1, d0, d1);
        float2 wv = *(const float2*)&ew[e0 + i];
        if ((unsigned)s0 < N_NODES && (unsigned)(d0 - p0) < PSIZE) {
            unsigned pos = atomicAdd(&lcur[d0 - p0], 1u);
            unsigned slot = off[d0] + pref[d0 - p0] + pos;
            buck[slot] = make_int2(s0, __float_as_int(dinv[s0] * wv.x * dinv[d0]));
        }
        if ((unsigned)s1 < N_NODES && (unsigned)(d1 - p0) < PSIZE) {
            unsigned pos = atomicAdd(&lcur[d1 - p0], 1u);
            unsigned slot = off[d1] + pref[d1 - p0] + pos;
            buck[slot] = make_int2(s1, __float_as_int(dinv[s1] * wv.y * dinv[d1]));
        }
    }
}

// h = x @ W^T.  64 nodes/block, 256 threads. (validated R1-R3)
__global__ __launch_bounds__(256) void gemm_kernel(const float* __restrict__ x,
                                                   const float* __restrict__ W,
                                                   float* __restrict__ h) {
    __shared__ float xs[64 * 132];
    __shared__ float wt[32 * 256];
    const int tid = threadIdx.x;
    const int n0 = blockIdx.x * 64;
#pragma unroll
    for (int i = 0; i < 8; ++i) {
        int f4 = tid + i * 256;
        int n = f4 >> 5;
        int k = (f4 & 31) << 2;
        float4 v = make_float4(0.f, 0.f, 0.f, 0.f);
        if (n0 + n < N_NODES) v = *(const float4*)&x[(n0 + n) * F_IN + k];
        *(float4*)&xs[n * 132 + k] = v;
    }
#pragma unroll
    for (int i = 0; i < 8; ++i) {
        int o = tid & 63;
        int kc = (tid >> 6) + i * 4;
        float4 v = *(const float4*)&W[o * F_IN + kc * 4];
        *(float4*)&wt[kc * 256 + o * 4] = v;
    }
    __syncthreads();
    const int og = tid & 7;
    const int ng = tid >> 3;
    float acc0[8], acc1[8];
#pragma unroll
    for (int j = 0; j < 8; ++j) { acc0[j] = 0.f; acc1[j] = 0.f; }
    const float4* xs4a = (const float4*)&xs[ng * 132];
    const float4* xs4b = (const float4*)&xs[(ng + 32) * 132];
    const float4* wt4 = (const float4*)wt;
#pragma unroll 4
    for (int kc = 0; kc < 32; ++kc) {
        float4 xa = xs4a[kc];
        float4 xb = xs4b[kc];
#pragma unroll
        for (int j = 0; j < 8; ++j) {
            float4 wv = wt4[kc * 64 + og + 8 * j];
            acc0[j] += xa.x * wv.x + xa.y * wv.y + xa.z * wv.z + xa.w * wv.w;
            acc1[j] += xb.x * wv.x + xb.y * wv.y + xb.z * wv.z + xb.w * wv.w;
        }
    }
    const int na = n0 + ng, nb = n0 + ng + 32;
#pragma unroll
    for (int j = 0; j < 8; ++j) {
        if (na < N_NODES) h[na * F_OUT + og + 8 * j] = acc0[j];
        if (nb < N_NODES) h[nb * F_OUT + og + 8 * j] = acc1[j];
    }
}

// Wave-per-node aggregation (validated R3): 64 lanes = 4 edge slots x 16 ch lanes.
#define AGG_BLOCKS 2048
#define AGG_WAVES  (AGG_BLOCKS * 4)
__global__ __launch_bounds__(256) void aggregate_kernel(
    const float* __restrict__ h, const float* __restrict__ dinv,
    const unsigned* __restrict__ off, const unsigned* __restrict__ cnt,
    const int2* __restrict__ buck, float* __restrict__ out,
    float* __restrict__ sums) {
    const int tid = threadIdx.x;
    const int wv = tid >> 6;
    const int lane = tid & 63;
    const int es = lane >> 4;
    const int cl = lane & 15;
    float s1[4] = {0.f, 0.f, 0.f, 0.f};
    float s2[4] = {0.f, 0.f, 0.f, 0.f};

    for (int n = blockIdx.x * 4 + wv; n < N_NODES; n += AGG_WAVES) {
        const unsigned o = off[n];
        const unsigned c = cnt[n];
        float4 a0 = make_float4(0.f, 0.f, 0.f, 0.f);
        float4 a1 = make_float4(0.f, 0.f, 0.f, 0.f);
        unsigned j = es;
        for (; j + 4 < c; j += 8) {
            int2 b1 = buck[o + j];
            int2 b2 = buck[o + j + 4];
            float4 h1 = *(const float4*)&h[(long)b1.x * F_OUT + cl * 4];
            float4 h2 = *(const float4*)&h[(long)b2.x * F_OUT + cl * 4];
            float w1 = __int_as_float(b1.y);
            float w2 = __int_as_float(b2.y);
            a0.x += h1.x * w1; a0.y += h1.y * w1; a0.z += h1.z * w1; a0.w += h1.w * w1;
            a1.x += h2.x * w2; a1.y += h2.y * w2; a1.z += h2.z * w2; a1.w += h2.w * w2;
        }
        if (j < c) {
            int2 bb = buck[o + j];
            float w = __int_as_float(bb.y);
            float4 hv = *(const float4*)&h[(long)bb.x * F_OUT + cl * 4];
            a0.x += hv.x * w; a0.y += hv.y * w; a0.z += hv.z * w; a0.w += hv.w * w;
        }
        a0.x += a1.x; a0.y += a1.y; a0.z += a1.z; a0.w += a1.w;
        a0.x += __shfl_xor(a0.x, 16); a0.y += __shfl_xor(a0.y, 16);
        a0.z += __shfl_xor(a0.z, 16); a0.w += __shfl_xor(a0.w, 16);
        a0.x += __shfl_xor(a0.x, 32); a0.y += __shfl_xor(a0.y, 32);
        a0.z += __shfl_xor(a0.z, 32); a0.w += __shfl_xor(a0.w, 32);
        if (es == 0) {
            float di = dinv[n];
            float sw = di * di;
            float4 hn = *(const float4*)&h[(long)n * F_OUT + cl * 4];
            a0.x = fmaxf(fmaf(hn.x, sw, a0.x), 0.f);
            a0.y = fmaxf(fmaf(hn.y, sw, a0.y), 0.f);
            a0.z = fmaxf(fmaf(hn.z, sw, a0.z), 0.f);
            a0.w = fmaxf(fmaf(hn.w, sw, a0.w), 0.f);
            *(float4*)&out[(long)n * F_OUT + cl * 4] = a0;
            s1[0] += a0.x; s1[1] += a0.y; s1[2] += a0.z; s1[3] += a0.w;
            s2[0] += a0.x * a0.x; s2[1] += a0.y * a0.y;
            s2[2] += a0.z * a0.z; s2[3] += a0.w * a0.w;
        }
    }
    __shared__ float l1[256];
    __shared__ float l2[256];
    if (es == 0) {
#pragma unroll
        for (int k = 0; k < 4; ++k) {
            l1[wv * 64 + cl * 4 + k] = s1[k];
            l2[wv * 64 + cl * 4 + k] = s2[k];
        }
    }
    __syncthreads();
    if (tid < 64) {
        float b1 = l1[tid] + l1[64 + tid] + l1[128 + tid] + l1[192 + tid];
        float b2 = l2[tid] + l2[64 + tid] + l2[128 + tid] + l2[192 + tid];
        atomicAdd(&sums[tid], b1);
        atomicAdd(&sums[64 + tid], b2);
    }
}

__global__ void finalize_kernel(float* __restrict__ sums,
                                const float* __restrict__ gamma,
                                const float* __restrict__ beta) {
    int c = threadIdx.x;
    const float inv_n = 1.0f / (float)N_NODES;
    float mean = sums[c] * inv_n;
    float var = sums[64 + c] * inv_n - mean * mean;
    float rs = rsqrtf(var + BN_EPS);
    float sc = rs * gamma[c];
    sums[c] = sc;
    sums[64 + c] = beta[c] - mean * sc;
}

__global__ __launch_bounds__(256) void apply_kernel(float* __restrict__ agg,
                                                    const float* __restrict__ sums) {
    int i = blockIdx.x * blockDim.x + threadIdx.x;
    if (i >= N_NODES * 16) return;
    int c4 = (i & 15) << 2;
    float4 v = ((float4*)agg)[i];
    v.x = v.x * sums[c4 + 0] + sums[64 + c4 + 0];
    v.y = v.y * sums[c4 + 1] + sums[64 + c4 + 1];
    v.z = v.z * sums[c4 + 2] + sums[64 + c4 + 2];
    v.w = v.w * sums[c4 + 3] + sums[64 + c4 + 3];
    ((float4*)agg)[i] = v;
}

extern "C" void kernel_launch(void* const* d_in, const int* in_sizes, int n_in,
                              void* d_out, int out_size, void* d_ws, size_t ws_size,
                              hipStream_t stream) {
    const float* x     = (const float*)d_in[0];
    const void*  ei    = d_in[1];
    const float* ew    = (const float*)d_in[2];
    const float* W     = (const float*)d_in[3];
    const float* gamma = (const float*)d_in[4];
    const float* beta  = (const float*)d_in[5];
    float* out = (float*)d_out;
    float* ws  = (float*)d_ws;

    float*    hp      = ws;                       // partial, then h (after place)
    unsigned* partial = (unsigned*)ws;
    int2*     buck    = (int2*)(ws + 6400000);
    float*    dinv    = ws + 9600000;
    float*    sums    = ws + 9700000;
    unsigned* cnt     = (unsigned*)(ws + 9700128);
    unsigned* off     = (unsigned*)(ws + 9800128);
    unsigned* bsum    = (unsigned*)(ws + 9900128);
    int*      flag    = (int*)(ws + 9900256);

    detect_kernel<<<1, 256, 0, stream>>>(ei, flag);
    count_kernel<<<NPART * NCHUNK, 512, 0, stream>>>(ei, partial, flag);
    reduce_kernel<<<(N_NODES + 255) / 256, 256, 0, stream>>>(partial, cnt, dinv, sums);
    scan1_kernel<<<SCAN_NB, 256, 0, stream>>>(cnt, off, bsum);
    scan2_kernel<<<1, 128, 0, stream>>>(bsum);
    scan3_kernel<<<(N_NODES + 255) / 256, 256, 0, stream>>>(off, bsum);
    place_kernel<<<NPART * NCHUNK, 512, 0, stream>>>(ei, ew, dinv, off, partial, buck, flag);
    gemm_kernel<<<(N_NODES + 63) / 64, 256, 0, stream>>>(x, W, hp);   // overwrites partial
    aggregate_kernel<<<AGG_BLOCKS, 256, 0, stream>>>(hp, dinv, off, cnt, buck, out, sums);
    finalize_kernel<<<1, 64, 0, stream>>>(sums, gamma, beta);
    apply_kernel<<<(N_NODES * 16 + 255) / 256, 256, 0, stream>>>(out, sums);
}

// Round 5
// 363.365 us; speedup vs baseline: 4.4716x; 1.0300x over previous
//
#include <hip/hip_runtime.h>

#define N_NODES 100000
#define N_EDGES 1600000
#define F_IN 128
#define F_OUT 64
#define BN_EPS 1e-5f

#define NPART 8            // node partitions
#define NCHUNK 32          // edge chunks
#define PSIZE 12500        // nodes per partition
#define CHUNK_E 50000      // edges per chunk

#define SCAN_BLK 1024
#define SCAN_NB  ((N_NODES + SCAN_BLK - 1) / SCAN_BLK)   // 98

// ---------------- workspace layout (4-byte elements) ----------------
// s32    : [0,        1600000)   edge sources, int32
// d32    : [1600000,  3200000)   edge dests, int32
// partial: [3200000,  6400000)   chunk histograms/prefixes; THEN hb (bf16 h) aliases
// buck   : [6400000,  9600000)   int2 {src, norm-bits} per edge
// dinv   : [9600000,  9700000)
// sums   : [9700000,  9700128)
// cnt    : [9700128,  9800128)
// off    : [9800128,  9900128)
// bsum   : [9900128,  9900256)
// flag   : [9900256]

__device__ __forceinline__ unsigned short f2bf(float x) {
    unsigned u = __float_as_uint(x);
    u += 0x7fffu + ((u >> 16) & 1u);   // RTNE
    return (unsigned short)(u >> 16);
}
__device__ __forceinline__ float4 bf4(uint2 p) {
    return make_float4(__int_as_float((int)(p.x << 16)),
                       __int_as_float((int)(p.x & 0xffff0000u)),
                       __int_as_float((int)(p.y << 16)),
                       __int_as_float((int)(p.y & 0xffff0000u)));
}

__global__ void detect_kernel(const void* __restrict__ ei, int* __restrict__ flag) {
    __shared__ int bad;
    if (threadIdx.x == 0) bad = 0;
    __syncthreads();
    int local = 0;
    for (int i = threadIdx.x; i < 1024; i += blockDim.x) {
        long long v = ((const long long*)ei)[i];
        if (v < 0 || v >= N_NODES) local = 1;
    }
    if (local) atomicOr(&bad, 1);
    __syncthreads();
    if (threadIdx.x == 0) *flag = bad ? 0 : 1;
}

// One-time ei -> int32 SoA. 4 edges/thread.
__global__ __launch_bounds__(256) void convert_kernel(const void* __restrict__ ei,
                                                      int* __restrict__ s32,
                                                      int* __restrict__ d32,
                                                      const int* __restrict__ flag) {
    int i = blockIdx.x * 256 + threadIdx.x;   // int4 index
    if (i >= N_EDGES / 4) return;
    int4 s, d;
    if (*flag) {
        const long long* q = (const long long*)ei;
        longlong2 a = *(const longlong2*)&q[i * 4];
        longlong2 b = *(const longlong2*)&q[i * 4 + 2];
        s = make_int4((int)a.x, (int)a.y, (int)b.x, (int)b.y);
        longlong2 c = *(const longlong2*)&q[N_EDGES + i * 4];
        longlong2 e = *(const longlong2*)&q[N_EDGES + i * 4 + 2];
        d = make_int4((int)c.x, (int)c.y, (int)e.x, (int)e.y);
    } else {
        s = ((const int4*)ei)[i];
        d = ((const int4*)ei)[N_EDGES / 4 + i];
    }
    ((int4*)s32)[i] = s;
    ((int4*)d32)[i] = d;
}

// Block (p,b): histogram chunk b for node range p into LDS, flush plain stores.
// Packed u32 bin: src-degree low16, dst-count high16. 4 edges/thread.
__global__ __launch_bounds__(512) void count_kernel(const int* __restrict__ s32,
                                                    const int* __restrict__ d32,
                                                    unsigned* __restrict__ partial) {
    __shared__ unsigned bins[PSIZE];
    const int tid = threadIdx.x;
    const int p = blockIdx.x % NPART;
    const int b = blockIdx.x / NPART;
    const int p0 = p * PSIZE;
    for (int i = tid; i < PSIZE; i += 512) bins[i] = 0u;
    __syncthreads();
    const int4* sp = (const int4*)(s32 + b * CHUNK_E);
    const int4* dp = (const int4*)(d32 + b * CHUNK_E);
    for (int i = tid; i < CHUNK_E / 4; i += 512) {
        int4 s = sp[i];
        int4 d = dp[i];
#define CNT1(sk, dk) \
        if ((unsigned)((sk) - p0) < PSIZE) atomicAdd(&bins[(sk) - p0], 1u); \
        if ((unsigned)(sk) < N_NODES && (unsigned)((dk) - p0) < PSIZE) \
            atomicAdd(&bins[(dk) - p0], 0x10000u);
        CNT1(s.x, d.x) CNT1(s.y, d.y) CNT1(s.z, d.z) CNT1(s.w, d.w)
#undef CNT1
    }
    __syncthreads();
    unsigned* dst = &partial[(unsigned)blockIdx.x * PSIZE];
    for (int i = tid; i < PSIZE; i += 512) dst[i] = bins[i];
}

// Per node: deg -> dinv, cnt total; overwrite each chunk slice entry with the
// exclusive prefix of cnt across chunks (placement base).
__global__ __launch_bounds__(256) void reduce_kernel(unsigned* __restrict__ partial,
                                                     unsigned* __restrict__ cnt,
                                                     float* __restrict__ dinv,
                                                     float* __restrict__ sums) {
    int n = blockIdx.x * 256 + threadIdx.x;
    if (n < 128) sums[n] = 0.f;
    if (n >= N_NODES) return;
    unsigned p = (unsigned)n / PSIZE;
    unsigned i = (unsigned)n % PSIZE;
    unsigned run = 0, degt = 0;
    unsigned addr = p * PSIZE + i;
#pragma unroll 8
    for (int b = 0; b < NCHUNK; ++b) {
        unsigned v = partial[addr];
        partial[addr] = run;
        run += v >> 16;
        degt += v & 0xFFFFu;
        addr += NPART * PSIZE;
    }
    cnt[n] = run;
    dinv[n] = rsqrtf((float)(degt + 1u));   // +1 self loop
}

// ---- exclusive scan of cnt -> off ----
__global__ __launch_bounds__(256) void scan1_kernel(const unsigned* __restrict__ cnt,
                                                    unsigned* __restrict__ off,
                                                    unsigned* __restrict__ bsum) {
    __shared__ unsigned s[256];
    const int tid = threadIdx.x;
    const int base = blockIdx.x * SCAN_BLK + tid * 4;
    unsigned v[4];
#pragma unroll
    for (int k = 0; k < 4; ++k) v[k] = (base + k < N_NODES) ? cnt[base + k] : 0u;
    unsigned tsum = v[0] + v[1] + v[2] + v[3];
    s[tid] = tsum;
    __syncthreads();
    for (int d = 1; d < 256; d <<= 1) {
        unsigned t = (tid >= d) ? s[tid - d] : 0u;
        __syncthreads();
        s[tid] += t;
        __syncthreads();
    }
    unsigned run = s[tid] - tsum;
#pragma unroll
    for (int k = 0; k < 4; ++k) {
        if (base + k < N_NODES) off[base + k] = run;
        run += v[k];
    }
    if (tid == 255) bsum[blockIdx.x] = s[255];
}

__global__ __launch_bounds__(128) void scan2_kernel(unsigned* __restrict__ bsum) {
    __shared__ unsigned s[128];
    const int tid = threadIdx.x;
    unsigned v = (tid < SCAN_NB) ? bsum[tid] : 0u;
    s[tid] = v;
    __syncthreads();
    for (int d = 1; d < 128; d <<= 1) {
        unsigned t = (tid >= d) ? s[tid - d] : 0u;
        __syncthreads();
        s[tid] += t;
        __syncthreads();
    }
    if (tid < SCAN_NB) bsum[tid] = s[tid] - v;
}

__global__ void scan3_kernel(unsigned* __restrict__ off, const unsigned* __restrict__ bsum) {
    int i = blockIdx.x * blockDim.x + threadIdx.x;
    if (i < N_NODES) off[i] += bsum[i >> 10];
}

// Deterministic placement: slot = off[d] + chunk-prefix + LDS-local rank.
__global__ __launch_bounds__(512) void place_kernel(const int* __restrict__ s32,
                                                    const int* __restrict__ d32,
                                                    const float* __restrict__ ew,
                                                    const float* __restrict__ dinv,
                                                    const unsigned* __restrict__ off,
                                                    const unsigned* __restrict__ partial,
                                                    int2* __restrict__ buck) {
    __shared__ unsigned lcur[PSIZE];
    const int tid = threadIdx.x;
    const int p = blockIdx.x % NPART;
    const int b = blockIdx.x / NPART;
    const int p0 = p * PSIZE;
    for (int i = tid; i < PSIZE; i += 512) lcur[i] = 0u;
    __syncthreads();
    const int4* sp = (const int4*)(s32 + b * CHUNK_E);
    const int4* dp = (const int4*)(d32 + b * CHUNK_E);
    const float4* wp = (const float4*)(ew + b * CHUNK_E);
    const unsigned* pref = &partial[(unsigned)blockIdx.x * PSIZE];
    for (int i = tid; i < CHUNK_E / 4; i += 512) {
        int4 s = sp[i];
        int4 d = dp[i];
        float4 w = wp[i];
#define PLACE1(sk, dk, wk) \
        if ((unsigned)(sk) < N_NODES && (unsigned)((dk) - p0) < PSIZE) { \
            unsigned pos = atomicAdd(&lcur[(dk) - p0], 1u); \
            unsigned slot = off[dk] + pref[(dk) - p0] + pos; \
            buck[slot] = make_int2((sk), __float_as_int(dinv[sk] * (wk) * dinv[dk])); \
        }
        PLACE1(s.x, d.x, w.x) PLACE1(s.y, d.y, w.y)
        PLACE1(s.z, d.z, w.z) PLACE1(s.w, d.w, w.w)
#undef PLACE1
    }
}

// h = x @ W^T, stored bf16.  64 nodes/block, 256 threads.
__global__ __launch_bounds__(256) void gemm_kernel(const float* __restrict__ x,
                                                   const float* __restrict__ W,
                                                   unsigned short* __restrict__ hb) {
    __shared__ float xs[64 * 132];
    __shared__ float wt[32 * 256];
    const int tid = threadIdx.x;
    const int n0 = blockIdx.x * 64;
#pragma unroll
    for (int i = 0; i < 8; ++i) {
        int f4 = tid + i * 256;
        int n = f4 >> 5;
        int k = (f4 & 31) << 2;
        float4 v = make_float4(0.f, 0.f, 0.f, 0.f);
        if (n0 + n < N_NODES) v = *(const float4*)&x[(n0 + n) * F_IN + k];
        *(float4*)&xs[n * 132 + k] = v;
    }
#pragma unroll
    for (int i = 0; i < 8; ++i) {
        int o = tid & 63;
        int kc = (tid >> 6) + i * 4;
        float4 v = *(const float4*)&W[o * F_IN + kc * 4];
        *(float4*)&wt[kc * 256 + o * 4] = v;
    }
    __syncthreads();
    const int og = tid & 7;
    const int ng = tid >> 3;
    float acc0[8], acc1[8];
#pragma unroll
    for (int j = 0; j < 8; ++j) { acc0[j] = 0.f; acc1[j] = 0.f; }
    const float4* xs4a = (const float4*)&xs[ng * 132];
    const float4* xs4b = (const float4*)&xs[(ng + 32) * 132];
    const float4* wt4 = (const float4*)wt;
#pragma unroll 4
    for (int kc = 0; kc < 32; ++kc) {
        float4 xa = xs4a[kc];
        float4 xb = xs4b[kc];
#pragma unroll
        for (int j = 0; j < 8; ++j) {
            float4 wv = wt4[kc * 64 + og + 8 * j];
            acc0[j] += xa.x * wv.x + xa.y * wv.y + xa.z * wv.z + xa.w * wv.w;
            acc1[j] += xb.x * wv.x + xb.y * wv.y + xb.z * wv.z + xb.w * wv.w;
        }
    }
    const int na = n0 + ng, nb = n0 + ng + 32;
#pragma unroll
    for (int j = 0; j < 8; ++j) {
        if (na < N_NODES) hb[na * F_OUT + og + 8 * j] = f2bf(acc0[j]);
        if (nb < N_NODES) hb[nb * F_OUT + og + 8 * j] = f2bf(acc1[j]);
    }
}

// Wave-per-node aggregation: 64 lanes = 4 edge slots x 16 channel lanes.
// h rows are bf16 (128 B = one cache line per edge gather).
#define AGG_BLOCKS 2048
#define AGG_WAVES  (AGG_BLOCKS * 4)
__global__ __launch_bounds__(256) void aggregate_kernel(
    const unsigned short* __restrict__ hb, const float* __restrict__ dinv,
    const unsigned* __restrict__ off, const unsigned* __restrict__ cnt,
    const int2* __restrict__ buck, float* __restrict__ out,
    float* __restrict__ sums) {
    const int tid = threadIdx.x;
    const int wv = tid >> 6;
    const int lane = tid & 63;
    const int es = lane >> 4;
    const int cl = lane & 15;
    float s1[4] = {0.f, 0.f, 0.f, 0.f};
    float s2[4] = {0.f, 0.f, 0.f, 0.f};

    for (int n = blockIdx.x * 4 + wv; n < N_NODES; n += AGG_WAVES) {
        const unsigned o = off[n];
        const unsigned c = cnt[n];
        float4 a0 = make_float4(0.f, 0.f, 0.f, 0.f);
        float4 a1 = make_float4(0.f, 0.f, 0.f, 0.f);
        unsigned j = es;
        for (; j + 4 < c; j += 8) {
            int2 b1 = buck[o + j];
            int2 b2 = buck[o + j + 4];
            uint2 p1 = ((const uint2*)(hb + ((long)b1.x << 6)))[cl];
            uint2 p2 = ((const uint2*)(hb + ((long)b2.x << 6)))[cl];
            float4 h1 = bf4(p1);
            float4 h2 = bf4(p2);
            float w1 = __int_as_float(b1.y);
            float w2 = __int_as_float(b2.y);
            a0.x += h1.x * w1; a0.y += h1.y * w1; a0.z += h1.z * w1; a0.w += h1.w * w1;
            a1.x += h2.x * w2; a1.y += h2.y * w2; a1.z += h2.z * w2; a1.w += h2.w * w2;
        }
        if (j < c) {
            int2 bb = buck[o + j];
            float w = __int_as_float(bb.y);
            float4 hv = bf4(((const uint2*)(hb + ((long)bb.x << 6)))[cl]);
            a0.x += hv.x * w; a0.y += hv.y * w; a0.z += hv.z * w; a0.w += hv.w * w;
        }
        a0.x += a1.x; a0.y += a1.y; a0.z += a1.z; a0.w += a1.w;
        a0.x += __shfl_xor(a0.x, 16); a0.y += __shfl_xor(a0.y, 16);
        a0.z += __shfl_xor(a0.z, 16); a0.w += __shfl_xor(a0.w, 16);
        a0.x += __shfl_xor(a0.x, 32); a0.y += __shfl_xor(a0.y, 32);
        a0.z += __shfl_xor(a0.z, 32); a0.w += __shfl_xor(a0.w, 32);
        if (es == 0) {
            float di = dinv[n];
            float sw = di * di;
            float4 hn = bf4(((const uint2*)(hb + ((long)n << 6)))[cl]);
            a0.x = fmaxf(fmaf(hn.x, sw, a0.x), 0.f);
            a0.y = fmaxf(fmaf(hn.y, sw, a0.y), 0.f);
            a0.z = fmaxf(fmaf(hn.z, sw, a0.z), 0.f);
            a0.w = fmaxf(fmaf(hn.w, sw, a0.w), 0.f);
            *(float4*)&out[(long)n * F_OUT + cl * 4] = a0;
            s1[0] += a0.x; s1[1] += a0.y; s1[2] += a0.z; s1[3] += a0.w;
            s2[0] += a0.x * a0.x; s2[1] += a0.y * a0.y;
            s2[2] += a0.z * a0.z; s2[3] += a0.w * a0.w;
        }
    }
    __shared__ float l1[256];
    __shared__ float l2[256];
    if (es == 0) {
#pragma unroll
        for (int k = 0; k < 4; ++k) {
            l1[wv * 64 + cl * 4 + k] = s1[k];
            l2[wv * 64 + cl * 4 + k] = s2[k];
        }
    }
    __syncthreads();
    if (tid < 64) {
        float b1 = l1[tid] + l1[64 + tid] + l1[128 + tid] + l1[192 + tid];
        float b2 = l2[tid] + l2[64 + tid] + l2[128 + tid] + l2[192 + tid];
        atomicAdd(&sums[tid], b1);
        atomicAdd(&sums[64 + tid], b2);
    }
}

__global__ void finalize_kernel(float* __restrict__ sums,
                                const float* __restrict__ gamma,
                                const float* __restrict__ beta) {
    int c = threadIdx.x;
    const float inv_n = 1.0f / (float)N_NODES;
    float mean = sums[c] * inv_n;
    float var = sums[64 + c] * inv_n - mean * mean;
    float rs = rsqrtf(var + BN_EPS);
    float sc = rs * gamma[c];
    sums[c] = sc;
    sums[64 + c] = beta[c] - mean * sc;
}

__global__ __launch_bounds__(256) void apply_kernel(float* __restrict__ agg,
                                                    const float* __restrict__ sums) {
    int i = blockIdx.x * blockDim.x + threadIdx.x;
    if (i >= N_NODES * 16) return;
    int c4 = (i & 15) << 2;
    float4 v = ((float4*)agg)[i];
    v.x = v.x * sums[c4 + 0] + sums[64 + c4 + 0];
    v.y = v.y * sums[c4 + 1] + sums[64 + c4 + 1];
    v.z = v.z * sums[c4 + 2] + sums[64 + c4 + 2];
    v.w = v.w * sums[c4 + 3] + sums[64 + c4 + 3];
    ((float4*)agg)[i] = v;
}

extern "C" void kernel_launch(void* const* d_in, const int* in_sizes, int n_in,
                              void* d_out, int out_size, void* d_ws, size_t ws_size,
                              hipStream_t stream) {
    const float* x     = (const float*)d_in[0];
    const void*  ei    = d_in[1];
    const float* ew    = (const float*)d_in[2];
    const float* W     = (const float*)d_in[3];
    const float* gamma = (const float*)d_in[4];
    const float* beta  = (const float*)d_in[5];
    float* out = (float*)d_out;
    float* ws  = (float*)d_ws;

    int*            s32     = (int*)ws;
    int*            d32     = (int*)(ws + 1600000);
    unsigned*       partial = (unsigned*)(ws + 3200000);
    unsigned short* hb      = (unsigned short*)(ws + 3200000);  // aliases partial
    int2*           buck    = (int2*)(ws + 6400000);
    float*          dinv    = ws + 9600000;
    float*          sums    = ws + 9700000;
    unsigned*       cnt     = (unsigned*)(ws + 9700128);
    unsigned*       off     = (unsigned*)(ws + 9800128);
    unsigned*       bsum    = (unsigned*)(ws + 9900128);
    int*            flag    = (int*)(ws + 9900256);

    detect_kernel<<<1, 256, 0, stream>>>(ei, flag);
    convert_kernel<<<(N_EDGES / 4 + 255) / 256, 256, 0, stream>>>(ei, s32, d32, flag);
    count_kernel<<<NPART * NCHUNK, 512, 0, stream>>>(s32, d32, partial);
    reduce_kernel<<<(N_NODES + 255) / 256, 256, 0, stream>>>(partial, cnt, dinv, sums);
    scan1_kernel<<<SCAN_NB, 256, 0, stream>>>(cnt, off, bsum);
    scan2_kernel<<<1, 128, 0, stream>>>(bsum);
    scan3_kernel<<<(N_NODES + 255) / 256, 256, 0, stream>>>(off, bsum);
    place_kernel<<<NPART * NCHUNK, 512, 0, stream>>>(s32, d32, ew, dinv, off, partial, buck);
    gemm_kernel<<<(N_NODES + 63) / 64, 256, 0, stream>>>(x, W, hb);  // overwrites partial
    aggregate_kernel<<<AGG_BLOCKS, 256, 0, stream>>>(hb, dinv, off, cnt, buck, out, sums);
    finalize_kernel<<<1, 64, 0, stream>>>(sums, gamma, beta);
    apply_kernel<<<(N_NODES * 16 + 255) / 256, 256, 0, stream>>>(out, sums);
}

// Round 6
// 300.424 us; speedup vs baseline: 5.4085x; 1.2095x over previous
//
#include <hip/hip_runtime.h>

#define N_NODES 100000
#define N_EDGES 1600000
#define F_IN 128
#define F_OUT 64
#define BN_EPS 1e-5f

#define NPART 4            // node partitions
#define NCHUNK 64          // edge chunks
#define PSIZE 25000        // nodes per partition
#define CHUNK_E 25000      // edges per chunk

#define SCAN_BLK 1024
#define SCAN_NB  ((N_NODES + SCAN_BLK - 1) / SCAN_BLK)   // 98

// ---------------- workspace layout (4-byte elements) ----------------
// s32    : [0,        1600000)   edge sources, int32
// d32    : [1600000,  3200000)   edge dests, int32
// partial: [3200000,  6400000)   u16 per (chunk-block, node): (deg u8|cnt u8) then prefix;
//                                hb (bf16 h) aliases after place_kernel
// buck   : [6400000,  9600000)   int2 {src, norm-bits} per edge
// dinv   : [9600000,  9700000)
// sums   : [9700000,  9700128)
// cnt    : [9700128,  9800128)
// off    : [9800128,  9900128)
// bsum   : [9900128,  9900256)

typedef __attribute__((ext_vector_type(8))) short bf16x8;
typedef __attribute__((ext_vector_type(4))) float f32x4;

__device__ __forceinline__ unsigned short f2bf(float x) {
    unsigned u = __float_as_uint(x);
    u += 0x7fffu + ((u >> 16) & 1u);   // RTNE
    return (unsigned short)(u >> 16);
}
__device__ __forceinline__ float4 bf4(uint2 p) {
    return make_float4(__int_as_float((int)(p.x << 16)),
                       __int_as_float((int)(p.x & 0xffff0000u)),
                       __int_as_float((int)(p.y << 16)),
                       __int_as_float((int)(p.y & 0xffff0000u)));
}

// ei -> int32 SoA, with inline int64-vs-int32 detection (wave-uniform ballot;
// int32 data misreads as int64 values >= 2^32 w.p. ~1-2e-5 per sample, 64 samples).
__global__ __launch_bounds__(256) void convert_kernel(const void* __restrict__ ei,
                                                      int* __restrict__ s32,
                                                      int* __restrict__ d32) {
    const long long* q = (const long long*)ei;
    long long probe = q[threadIdx.x & 63];
    bool bad = (probe < 0 || probe >= N_NODES);
    int is64 = (__ballot(bad) == 0ULL);   // block-uniform

    int i = blockIdx.x * 256 + threadIdx.x;   // int4 index
    if (i >= N_EDGES / 4) return;
    int4 s, d;
    if (is64) {
        longlong2 a = *(const longlong2*)&q[i * 4];
        longlong2 b = *(const longlong2*)&q[i * 4 + 2];
        s = make_int4((int)a.x, (int)a.y, (int)b.x, (int)b.y);
        longlong2 c = *(const longlong2*)&q[N_EDGES + i * 4];
        longlong2 e = *(const longlong2*)&q[N_EDGES + i * 4 + 2];
        d = make_int4((int)c.x, (int)c.y, (int)e.x, (int)e.y);
    } else {
        s = ((const int4*)ei)[i];
        d = ((const int4*)ei)[N_EDGES / 4 + i];
    }
    ((int4*)s32)[i] = s;
    ((int4*)d32)[i] = d;
}

// Block (p,b): byte-packed histogram of chunk b for partition p.
// LDS word = 2 nodes x (deg u8, cnt u8). Flush as u32 pairs -> u16/node partial.
__global__ __launch_bounds__(512) void count_kernel(const int* __restrict__ s32,
                                                    const int* __restrict__ d32,
                                                    unsigned* __restrict__ partial32) {
    __shared__ unsigned bins[PSIZE / 2];
    const int tid = threadIdx.x;
    const int p = blockIdx.x % NPART;
    const int b = blockIdx.x / NPART;
    const int p0 = p * PSIZE;
    for (int i = tid; i < PSIZE / 2; i += 512) bins[i] = 0u;
    __syncthreads();
    const int4* sp = (const int4*)(s32 + b * CHUNK_E);
    const int4* dp = (const int4*)(d32 + b * CHUNK_E);
    for (int i = tid; i < CHUNK_E / 4; i += 512) {
        int4 s = sp[i];
        int4 d = dp[i];
#define C1(sk, dk) { \
        unsigned si = (unsigned)((sk) - p0); \
        if (si < PSIZE) atomicAdd(&bins[si >> 1], 1u << ((si & 1) * 16)); \
        unsigned dd = (unsigned)((dk) - p0); \
        if ((unsigned)(sk) < N_NODES && dd < PSIZE) \
            atomicAdd(&bins[dd >> 1], 256u << ((dd & 1) * 16)); }
        C1(s.x, d.x) C1(s.y, d.y) C1(s.z, d.z) C1(s.w, d.w)
#undef C1
    }
    __syncthreads();
    unsigned* dst = partial32 + (unsigned)blockIdx.x * (PSIZE / 2);
    for (int i = tid; i < PSIZE / 2; i += 512) dst[i] = bins[i];
}

// Per node: deg -> dinv, cnt total; overwrite each chunk entry with the
// exclusive cnt-prefix across chunks (u16; max total cnt ~50).
__global__ __launch_bounds__(256) void reduce_kernel(unsigned short* __restrict__ partial16,
                                                     unsigned* __restrict__ cnt,
                                                     float* __restrict__ dinv,
                                                     float* __restrict__ sums) {
    int n = blockIdx.x * 256 + threadIdx.x;
    if (n < 128) sums[n] = 0.f;
    if (n >= N_NODES) return;
    unsigned p = (unsigned)n / PSIZE;
    unsigned i = (unsigned)n % PSIZE;
    unsigned run = 0, degt = 0;
    unsigned addr = p * PSIZE + i;
#pragma unroll 8
    for (int c = 0; c < NCHUNK; ++c) {
        unsigned v = partial16[addr];
        partial16[addr] = (unsigned short)run;
        run += (v >> 8) & 0xffu;
        degt += v & 0xffu;
        addr += NPART * PSIZE;
    }
    cnt[n] = run;
    dinv[n] = rsqrtf((float)(degt + 1u));   // +1 self loop
}

// ---- exclusive scan of cnt -> off ----
__global__ __launch_bounds__(256) void scan1_kernel(const unsigned* __restrict__ cnt,
                                                    unsigned* __restrict__ off,
                                                    unsigned* __restrict__ bsum) {
    __shared__ unsigned s[256];
    const int tid = threadIdx.x;
    const int base = blockIdx.x * SCAN_BLK + tid * 4;
    unsigned v[4];
#pragma unroll
    for (int k = 0; k < 4; ++k) v[k] = (base + k < N_NODES) ? cnt[base + k] : 0u;
    unsigned tsum = v[0] + v[1] + v[2] + v[3];
    s[tid] = tsum;
    __syncthreads();
    for (int d = 1; d < 256; d <<= 1) {
        unsigned t = (tid >= d) ? s[tid - d] : 0u;
        __syncthreads();
        s[tid] += t;
        __syncthreads();
    }
    unsigned run = s[tid] - tsum;
#pragma unroll
    for (int k = 0; k < 4; ++k) {
        if (base + k < N_NODES) off[base + k] = run;
        run += v[k];
    }
    if (tid == 255) bsum[blockIdx.x] = s[255];
}

__global__ __launch_bounds__(128) void scan2_kernel(unsigned* __restrict__ bsum) {
    __shared__ unsigned s[128];
    const int tid = threadIdx.x;
    unsigned v = (tid < SCAN_NB) ? bsum[tid] : 0u;
    s[tid] = v;
    __syncthreads();
    for (int d = 1; d < 128; d <<= 1) {
        unsigned t = (tid >= d) ? s[tid - d] : 0u;
        __syncthreads();
        s[tid] += t;
        __syncthreads();
    }
    if (tid < SCAN_NB) bsum[tid] = s[tid] - v;
}

__global__ void scan3_kernel(unsigned* __restrict__ off, const unsigned* __restrict__ bsum) {
    int i = blockIdx.x * blockDim.x + threadIdx.x;
    if (i < N_NODES) off[i] += bsum[i >> 10];
}

// Deterministic placement: slot = off[d] + chunk-prefix(u16) + u8 LDS rank.
__global__ __launch_bounds__(512) void place_kernel(const int* __restrict__ s32,
                                                    const int* __restrict__ d32,
                                                    const float* __restrict__ ew,
                                                    const float* __restrict__ dinv,
                                                    const unsigned* __restrict__ off,
                                                    const unsigned short* __restrict__ partial16,
                                                    int2* __restrict__ buck) {
    __shared__ unsigned lcur[PSIZE / 4];   // u8 cursor per node
    const int tid = threadIdx.x;
    const int p = blockIdx.x % NPART;
    const int b = blockIdx.x / NPART;
    const int p0 = p * PSIZE;
    for (int i = tid; i < PSIZE / 4; i += 512) lcur[i] = 0u;
    __syncthreads();
    const int4* sp = (const int4*)(s32 + b * CHUNK_E);
    const int4* dp = (const int4*)(d32 + b * CHUNK_E);
    const float4* wp = (const float4*)(ew + b * CHUNK_E);
    const unsigned short* pref = partial16 + (unsigned)blockIdx.x * PSIZE;
    for (int i = tid; i < CHUNK_E / 4; i += 512) {
        int4 s = sp[i];
        int4 d = dp[i];
        float4 w = wp[i];
#define P1(sk, dk, wk) { \
        unsigned dd = (unsigned)((dk) - p0); \
        if ((unsigned)(sk) < N_NODES && dd < PSIZE) { \
            unsigned sh = (dd & 3) * 8; \
            unsigned old = atomicAdd(&lcur[dd >> 2], 1u << sh); \
            unsigned pos = (old >> sh) & 0xffu; \
            unsigned slot = off[dk] + pref[dd] + pos; \
            buck[slot] = make_int2((sk), __float_as_int(dinv[sk] * (wk) * dinv[dk])); } }
        P1(s.x, d.x, w.x) P1(s.y, d.y, w.y) P1(s.z, d.z, w.z) P1(s.w, d.w, w.w)
#undef P1
    }
}

// h = x @ W^T via MFMA bf16 16x16x32. Block = 4 waves x 16 nodes = 64 nodes.
// W staged once as bf16 in LDS [koct][out][8]; A-frags straight from global x.
// Layouts (HW-verified): A[m=lane&15][k=quad*8+j]; C/D row=quad*4+reg, col=lane&15.
__global__ __launch_bounds__(256) void gemm_kernel(const float* __restrict__ x,
                                                   const float* __restrict__ W,
                                                   unsigned short* __restrict__ hb) {
    __shared__ short wlds[16 * 64 * 8];   // 16 KB
    const int tid = threadIdx.x;
    const int n0 = blockIdx.x * 64;
    {
        int out = tid & 63;
        int kb = tid >> 6;
#pragma unroll
        for (int i = 0; i < 4; ++i) {
            int koct = kb + i * 4;
            const float* wp = &W[out * F_IN + koct * 8];
            float4 aa = *(const float4*)wp;
            float4 bb = *(const float4*)(wp + 4);
            bf16x8 f;
            f[0] = (short)f2bf(aa.x); f[1] = (short)f2bf(aa.y);
            f[2] = (short)f2bf(aa.z); f[3] = (short)f2bf(aa.w);
            f[4] = (short)f2bf(bb.x); f[5] = (short)f2bf(bb.y);
            f[6] = (short)f2bf(bb.z); f[7] = (short)f2bf(bb.w);
            ((bf16x8*)wlds)[koct * 64 + out] = f;
        }
    }
    __syncthreads();
    const int wv = tid >> 6;
    const int lane = tid & 63;
    const int m = lane & 15;
    const int quad = lane >> 4;
    const int row = n0 + wv * 16 + m;
    const bool rv = row < N_NODES;
    const float* xrow = &x[(long)row * F_IN + quad * 8];
    f32x4 acc0 = {0.f, 0.f, 0.f, 0.f};
    f32x4 acc1 = {0.f, 0.f, 0.f, 0.f};
    f32x4 acc2 = {0.f, 0.f, 0.f, 0.f};
    f32x4 acc3 = {0.f, 0.f, 0.f, 0.f};
#pragma unroll
    for (int kc = 0; kc < 4; ++kc) {
        bf16x8 a = {0, 0, 0, 0, 0, 0, 0, 0};
        if (rv) {
            float4 aa = *(const float4*)(xrow + kc * 32);
            float4 bb = *(const float4*)(xrow + kc * 32 + 4);
            a[0] = (short)f2bf(aa.x); a[1] = (short)f2bf(aa.y);
            a[2] = (short)f2bf(aa.z); a[3] = (short)f2bf(aa.w);
            a[4] = (short)f2bf(bb.x); a[5] = (short)f2bf(bb.y);
            a[6] = (short)f2bf(bb.z); a[7] = (short)f2bf(bb.w);
        }
        const bf16x8* wrow = &((const bf16x8*)wlds)[(kc * 4 + quad) * 64 + m];
        acc0 = __builtin_amdgcn_mfma_f32_16x16x32_bf16(a, wrow[0],  acc0, 0, 0, 0);
        acc1 = __builtin_amdgcn_mfma_f32_16x16x32_bf16(a, wrow[16], acc1, 0, 0, 0);
        acc2 = __builtin_amdgcn_mfma_f32_16x16x32_bf16(a, wrow[32], acc2, 0, 0, 0);
        acc3 = __builtin_amdgcn_mfma_f32_16x16x32_bf16(a, wrow[48], acc3, 0, 0, 0);
    }
#pragma unroll
    for (int r = 0; r < 4; ++r) {
        int node = n0 + wv * 16 + quad * 4 + r;
        if (node < N_NODES) {
            unsigned short* hr = &hb[(long)node * F_OUT + m];
            hr[0]  = f2bf(acc0[r]);
            hr[16] = f2bf(acc1[r]);
            hr[32] = f2bf(acc2[r]);
            hr[48] = f2bf(acc3[r]);
        }
    }
}

// Wave-per-node aggregation: 64 lanes = 4 edge slots x 16 channel lanes,
// 4x unroll -> 16 independent gather chains per wave.
#define AGG_BLOCKS 2048
#define AGG_WAVES  (AGG_BLOCKS * 4)
__global__ __launch_bounds__(256) void aggregate_kernel(
    const unsigned short* __restrict__ hb, const float* __restrict__ dinv,
    const unsigned* __restrict__ off, const unsigned* __restrict__ cnt,
    const int2* __restrict__ buck, float* __restrict__ out,
    float* __restrict__ sums) {
    const int tid = threadIdx.x;
    const int wv = tid >> 6;
    const int lane = tid & 63;
    const int es = lane >> 4;
    const int cl = lane & 15;
    float s1[4] = {0.f, 0.f, 0.f, 0.f};
    float s2[4] = {0.f, 0.f, 0.f, 0.f};

    for (int n = blockIdx.x * 4 + wv; n < N_NODES; n += AGG_WAVES) {
        const unsigned o = off[n];
        const unsigned c = cnt[n];
        float4 a0 = make_float4(0.f, 0.f, 0.f, 0.f);
        float4 a1 = make_float4(0.f, 0.f, 0.f, 0.f);
        float4 a2 = make_float4(0.f, 0.f, 0.f, 0.f);
        float4 a3 = make_float4(0.f, 0.f, 0.f, 0.f);
        unsigned j = es;
        for (; j + 12 < c; j += 16) {
            int2 b1 = buck[o + j];
            int2 b2 = buck[o + j + 4];
            int2 b3 = buck[o + j + 8];
            int2 b4 = buck[o + j + 12];
            float4 h1 = bf4(((const uint2*)(hb + ((long)b1.x << 6)))[cl]);
            float4 h2 = bf4(((const uint2*)(hb + ((long)b2.x << 6)))[cl]);
            float4 h3 = bf4(((const uint2*)(hb + ((long)b3.x << 6)))[cl]);
            float4 h4 = bf4(((const uint2*)(hb + ((long)b4.x << 6)))[cl]);
            float w1 = __int_as_float(b1.y), w2 = __int_as_float(b2.y);
            float w3 = __int_as_float(b3.y), w4 = __int_as_float(b4.y);
            a0.x += h1.x * w1; a0.y += h1.y * w1; a0.z += h1.z * w1; a0.w += h1.w * w1;
            a1.x += h2.x * w2; a1.y += h2.y * w2; a1.z += h2.z * w2; a1.w += h2.w * w2;
            a2.x += h3.x * w3; a2.y += h3.y * w3; a2.z += h3.z * w3; a2.w += h3.w * w3;
            a3.x += h4.x * w4; a3.y += h4.y * w4; a3.z += h4.z * w4; a3.w += h4.w * w4;
        }
        for (; j < c; j += 4) {
            int2 bb = buck[o + j];
            float w = __int_as_float(bb.y);
            float4 hv = bf4(((const uint2*)(hb + ((long)bb.x << 6)))[cl]);
            a0.x += hv.x * w; a0.y += hv.y * w; a0.z += hv.z * w; a0.w += hv.w * w;
        }
        a0.x += a1.x + a2.x + a3.x;
        a0.y += a1.y + a2.y + a3.y;
        a0.z += a1.z + a2.z + a3.z;
        a0.w += a1.w + a2.w + a3.w;
        a0.x += __shfl_xor(a0.x, 16); a0.y += __shfl_xor(a0.y, 16);
        a0.z += __shfl_xor(a0.z, 16); a0.w += __shfl_xor(a0.w, 16);
        a0.x += __shfl_xor(a0.x, 32); a0.y += __shfl_xor(a0.y, 32);
        a0.z += __shfl_xor(a0.z, 32); a0.w += __shfl_xor(a0.w, 32);
        if (es == 0) {
            float di = dinv[n];
            float sw = di * di;
            float4 hn = bf4(((const uint2*)(hb + ((long)n << 6)))[cl]);
            a0.x = fmaxf(fmaf(hn.x, sw, a0.x), 0.f);
            a0.y = fmaxf(fmaf(hn.y, sw, a0.y), 0.f);
            a0.z = fmaxf(fmaf(hn.z, sw, a0.z), 0.f);
            a0.w = fmaxf(fmaf(hn.w, sw, a0.w), 0.f);
            *(float4*)&out[(long)n * F_OUT + cl * 4] = a0;
            s1[0] += a0.x; s1[1] += a0.y; s1[2] += a0.z; s1[3] += a0.w;
            s2[0] += a0.x * a0.x; s2[1] += a0.y * a0.y;
            s2[2] += a0.z * a0.z; s2[3] += a0.w * a0.w;
        }
    }
    __shared__ float l1[256];
    __shared__ float l2[256];
    if (es == 0) {
#pragma unroll
        for (int k = 0; k < 4; ++k) {
            l1[wv * 64 + cl * 4 + k] = s1[k];
            l2[wv * 64 + cl * 4 + k] = s2[k];
        }
    }
    __syncthreads();
    if (tid < 64) {
        float b1 = l1[tid] + l1[64 + tid] + l1[128 + tid] + l1[192 + tid];
        float b2 = l2[tid] + l2[64 + tid] + l2[128 + tid] + l2[192 + tid];
        atomicAdd(&sums[tid], b1);
        atomicAdd(&sums[64 + tid], b2);
    }
}

__global__ void finalize_kernel(float* __restrict__ sums,
                                const float* __restrict__ gamma,
                                const float* __restrict__ beta) {
    int c = threadIdx.x;
    const float inv_n = 1.0f / (float)N_NODES;
    float mean = sums[c] * inv_n;
    float var = sums[64 + c] * inv_n - mean * mean;
    float rs = rsqrtf(var + BN_EPS);
    float sc = rs * gamma[c];
    sums[c] = sc;
    sums[64 + c] = beta[c] - mean * sc;
}

__global__ __launch_bounds__(256) void apply_kernel(float* __restrict__ agg,
                                                    const float* __restrict__ sums) {
    int i = blockIdx.x * blockDim.x + threadIdx.x;
    if (i >= N_NODES * 16) return;
    int c4 = (i & 15) << 2;
    float4 v = ((float4*)agg)[i];
    v.x = v.x * sums[c4 + 0] + sums[64 + c4 + 0];
    v.y = v.y * sums[c4 + 1] + sums[64 + c4 + 1];
    v.z = v.z * sums[c4 + 2] + sums[64 + c4 + 2];
    v.w = v.w * sums[c4 + 3] + sums[64 + c4 + 3];
    ((float4*)agg)[i] = v;
}

extern "C" void kernel_launch(void* const* d_in, const int* in_sizes, int n_in,
                              void* d_out, int out_size, void* d_ws, size_t ws_size,
                              hipStream_t stream) {
    const float* x     = (const float*)d_in[0];
    const void*  ei    = d_in[1];
    const float* ew    = (const float*)d_in[2];
    const float* W     = (const float*)d_in[3];
    const float* gamma = (const float*)d_in[4];
    const float* beta  = (const float*)d_in[5];
    float* out = (float*)d_out;
    float* ws  = (float*)d_ws;

    int*            s32       = (int*)ws;
    int*            d32       = (int*)(ws + 1600000);
    unsigned*       partial32 = (unsigned*)(ws + 3200000);
    unsigned short* partial16 = (unsigned short*)(ws + 3200000);
    unsigned short* hb        = (unsigned short*)(ws + 3200000);  // aliases partial
    int2*           buck      = (int2*)(ws + 6400000);
    float*          dinv      = ws + 9600000;
    float*          sums      = ws + 9700000;
    unsigned*       cnt       = (unsigned*)(ws + 9700128);
    unsigned*       off       = (unsigned*)(ws + 9800128);
    unsigned*       bsum      = (unsigned*)(ws + 9900128);

    convert_kernel<<<(N_EDGES / 4 + 255) / 256, 256, 0, stream>>>(ei, s32, d32);
    count_kernel<<<NPART * NCHUNK, 512, 0, stream>>>(s32, d32, partial32);
    reduce_kernel<<<(N_NODES + 255) / 256, 256, 0, stream>>>(partial16, cnt, dinv, sums);
    scan1_kernel<<<SCAN_NB, 256, 0, stream>>>(cnt, off, bsum);
    scan2_kernel<<<1, 128, 0, stream>>>(bsum);
    scan3_kernel<<<(N_NODES + 255) / 256, 256, 0, stream>>>(off, bsum);
    place_kernel<<<NPART * NCHUNK, 512, 0, stream>>>(s32, d32, ew, dinv, off, partial16, buck);
    gemm_kernel<<<(N_NODES + 63) / 64, 256, 0, stream>>>(x, W, hb);  // overwrites partial
    aggregate_kernel<<<AGG_BLOCKS, 256, 0, stream>>>(hb, dinv, off, cnt, buck, out, sums);
    finalize_kernel<<<1, 64, 0, stream>>>(sums, gamma, beta);
    apply_kernel<<<(N_NODES * 16 + 255) / 256, 256, 0, stream>>>(out, sums);
}